// Round 8
// baseline (628.396 us; speedup 1.0000x reference)
//
#include <hip/hip_runtime.h>

// ---------------------------------------------------------------------------
// GraphSAGE 3-layer forward.
//   CSR build (coarse-hist + two-pass LDS bucket) -> bf16 planes -> per-layer:
//   aggregate(mean, quarter-wave-per-node, packed hi|lo bf16 out)
//   -> MFMA GEMM [agg(hi/lo)|z(bf16)]@[Wl;Wr]^T + bias + L2norm + relu
//   -> final linear (MFMA).
// ---------------------------------------------------------------------------

typedef __bf16 bf16x8 __attribute__((ext_vector_type(8)));
typedef float  f32x4  __attribute__((ext_vector_type(4)));

#define MFMA16(a, b, c) __builtin_amdgcn_mfma_f32_16x16x32_bf16((a), (b), (c), 0, 0, 0)

__device__ __forceinline__ unsigned rne_bf16(float f) {
  unsigned u = __float_as_uint(f);
  unsigned r = u + 0x7FFFu + ((u >> 16) & 1u);
  return r >> 16;
}

__device__ __forceinline__ float bf_lo(unsigned u) { return __uint_as_float(u << 16); }
__device__ __forceinline__ float bf_hi(unsigned u) { return __uint_as_float(u & 0xFFFF0000u); }

// pack fp32 -> (hi bf16 <<16) | lo bf16
__device__ __forceinline__ unsigned pack_hl(float f) {
  unsigned h = rne_bf16(f);
  unsigned l = rne_bf16(f - __uint_as_float(h << 16));
  return (h << 16) | l;
}

// ---------------- CSR build ----------------
// pack = src | ((dst & 1023) << 17); requires N < 2^17, N/1024 <= 128.

__global__ __launch_bounds__(256) void histA_k(const int* __restrict__ dst,
                                               int* __restrict__ ghist, int E) {
  __shared__ int h[128];
  const int tid = threadIdx.x;
  if (tid < 128) h[tid] = 0;
  __syncthreads();
  const int e0 = blockIdx.x * 2048;
#pragma unroll
  for (int j = 0; j < 8; ++j) {
    int e = e0 + j * 256 + tid;
    if (e < E) atomicAdd(&h[dst[e] >> 10], 1);
  }
  __syncthreads();
  if (tid < 128 && h[tid]) atomicAdd(&ghist[tid], h[tid]);
}

__global__ void cscan_k(const int* __restrict__ ghist, int* __restrict__ cbase,
                        int* __restrict__ gcur, int E) {
  __shared__ int sd[128];
  const int tid = threadIdx.x;
  int v = ghist[tid];
  sd[tid] = v;
  __syncthreads();
  for (int off = 1; off < 128; off <<= 1) {
    int u = (tid >= off) ? sd[tid - off] : 0;
    __syncthreads();
    sd[tid] += u;
    __syncthreads();
  }
  int excl = sd[tid] - v;
  cbase[tid] = excl;
  gcur[tid] = excl;
  if (tid == 127) cbase[128] = sd[127];
}

__global__ __launch_bounds__(256) void bucketA_k(
    const int* __restrict__ src, const int* __restrict__ dst,
    int* __restrict__ gcur, unsigned* __restrict__ coarse, int E, int nc) {
  __shared__ int hist[128];
  __shared__ int sd[128];
  __shared__ int lpos[128];
  __shared__ int gbase[128];
  __shared__ unsigned stage[2048];
  __shared__ unsigned char sbuck[2048];

  const int tid = threadIdx.x;
  const int e0 = blockIdx.x * 2048;

  if (tid < 128) hist[tid] = 0;
  __syncthreads();

  int bv[8], pk[8];
#pragma unroll
  for (int j = 0; j < 8; ++j) {
    int e = e0 + j * 256 + tid;
    bv[j] = -1;
    if (e < E) {
      int s = src[e], d = dst[e];
      bv[j] = d >> 10;
      pk[j] = s | ((d & 1023) << 17);
      atomicAdd(&hist[bv[j]], 1);
    }
  }
  __syncthreads();

  if (tid < 128) sd[tid] = hist[tid];
  __syncthreads();
  for (int off = 1; off < 128; off <<= 1) {
    int t = 0;
    if (tid < 128 && tid >= off) t = sd[tid - off];
    __syncthreads();
    if (tid < 128) sd[tid] += t;
    __syncthreads();
  }
  if (tid < 128) {
    int excl = sd[tid] - hist[tid];
    lpos[tid] = excl;
    gbase[tid] = (tid < nc && hist[tid] > 0) ? atomicAdd(&gcur[tid], hist[tid]) : 0;
  }
  __syncthreads();

#pragma unroll
  for (int j = 0; j < 8; ++j) {
    if (bv[j] >= 0) {
      int slot = atomicAdd(&lpos[bv[j]], 1);
      stage[slot] = (unsigned)pk[j];
      sbuck[slot] = (unsigned char)bv[j];
    }
  }
  __syncthreads();

  const int total = sd[127];
  for (int i = tid; i < total; i += 256) {
    int b = sbuck[i];
    int excl = sd[b] - hist[b];
    coarse[gbase[b] + (i - excl)] = stage[i];
  }
}

__global__ __launch_bounds__(256) void bucketB_k(
    const int* __restrict__ cbase, const unsigned* __restrict__ coarse,
    int* __restrict__ esrc, int* __restrict__ offsets,
    float* __restrict__ inv_cnt, int n, int E) {
  __shared__ int hcnt[1024];
  __shared__ int cur[1024];
  __shared__ int sd[256];

  const int tid = threadIdx.x;
  const int b = blockIdx.x;
  const int base = b * 1024;
  const int nn = (n - base < 1024) ? (n - base) : 1024;
  const int cbeg = cbase[b];
  const int cend = cbase[b + 1];

  for (int j = tid; j < 1024; j += 256) hcnt[j] = 0;
  __syncthreads();
  for (int idx = cbeg + tid; idx < cend; idx += 256)
    atomicAdd(&hcnt[coarse[idx] >> 17], 1);
  __syncthreads();

  int b0 = hcnt[tid * 4], b1 = hcnt[tid * 4 + 1];
  int b2 = hcnt[tid * 4 + 2], b3 = hcnt[tid * 4 + 3];
  int tot = b0 + b1 + b2 + b3;
  sd[tid] = tot;
  __syncthreads();
  for (int off = 1; off < 256; off <<= 1) {
    int u = (tid >= off) ? sd[tid - off] : 0;
    __syncthreads();
    sd[tid] += u;
    __syncthreads();
  }
  int excl = cbeg + sd[tid] - tot;
  cur[tid * 4]     = excl;
  cur[tid * 4 + 1] = excl + b0;
  cur[tid * 4 + 2] = excl + b0 + b1;
  cur[tid * 4 + 3] = excl + b0 + b1 + b2;
  __syncthreads();

  for (int j = tid; j < nn; j += 256) {
    offsets[base + j] = cur[j];
    int c = hcnt[j] > 1 ? hcnt[j] : 1;
    inv_cnt[base + j] = 1.0f / (float)c;
  }
  if (tid == 0 && base + nn >= n) offsets[n] = cend;
  __syncthreads();

  for (int idx = cbeg + tid; idx < cend; idx += 256) {
    unsigned p = coarse[idx];
    int pos = atomicAdd(&cur[p >> 17], 1);
    esrc[pos] = (int)(p & 0x1FFFFu);
  }
}

// ---------------- fp32 -> bf16 plane ----------------
__global__ void to_bf16_k(const float4* __restrict__ in, uint2* __restrict__ out, int n4) {
  int i = blockIdx.x * 256 + threadIdx.x;
  if (i >= n4) return;
  float4 f = in[i];
  uint2 o;
  o.x = rne_bf16(f.x) | (rne_bf16(f.y) << 16);
  o.y = rne_bf16(f.z) | (rne_bf16(f.w) << 16);
  out[i] = o;
}

// ---------------- weight fragment prep (hi/lo bf16, MFMA B-layout) ----------
__global__ void wfrag_prep_k(const float* __restrict__ Wl, const float* __restrict__ Wr,
                             unsigned short* __restrict__ wfrag) {
  int id = blockIdx.x * 256 + threadIdx.x;
  if (id >= 3 * 2 * 8 * 8 * 64) return;
  int l = id & 63;
  int c = (id >> 6) & 7;
  int t = (id >> 9) & 7;
  int p = (id >> 12) & 1;
  int layer = id >> 13;
  int col = t * 16 + (l & 15);
  int kbase = c * 32 + (l >> 4) * 8;
  unsigned short* dst = wfrag + (size_t)layer * 65536 +
                        ((((size_t)p * 8 + t) * 8 + c) * 64 + l) * 8;
#pragma unroll
  for (int j = 0; j < 8; ++j) {
    int k = kbase + j;
    float w = (k < 128) ? Wl[layer * 16384 + col * 128 + k]
                        : Wr[layer * 16384 + col * 128 + (k - 128)];
    unsigned h = rne_bf16(w);
    unsigned o;
    if (p == 0) o = h;
    else o = rne_bf16(w - __uint_as_float(h << 16));
    dst[j] = (unsigned short)o;
  }
}

__global__ void wlin_frag_k(const float* __restrict__ Wlin, unsigned short* __restrict__ wlf) {
  int id = blockIdx.x * 256 + threadIdx.x;
  if (id >= 3 * 4 * 64) return;
  int l = id & 63;
  int c = (id >> 6) & 3;
  int t = id >> 8;
  int col = t * 16 + (l & 15);
  int kbase = c * 32 + (l >> 4) * 8;
  unsigned short* dst = wlf + (size_t)id * 8;
#pragma unroll
  for (int j = 0; j < 8; ++j) {
    float w = (col < 40) ? Wlin[col * 128 + kbase + j] : 0.f;
    dst[j] = (unsigned short)rne_bf16(w);
  }
}

// ---------------- aggregation: quarter-wave (16 lanes) per node ------------
// Lane covers dims [l16*8, l16*8+8); 2-deep unroll -> 8 rows in flight/wave.
// No cross-lane reduce. Output: packed (hi<<16|lo) uint32 plane.
__global__ void aggregate_k(const unsigned short* __restrict__ zb,
                            const int* __restrict__ offsets,
                            const int* __restrict__ esrc,
                            const float* __restrict__ inv_cnt,
                            unsigned* __restrict__ aggp, int n) {
  int node = (blockIdx.x * 256 + threadIdx.x) >> 4;
  int l16 = threadIdx.x & 15;
  if (node >= n) return;
  int beg = offsets[node], end = offsets[node + 1];
  float a0 = 0.f, a1 = 0.f, a2 = 0.f, a3 = 0.f;
  float a4 = 0.f, a5 = 0.f, a6 = 0.f, a7 = 0.f;
  int t = beg;
  for (; t + 2 <= end; t += 2) {
    int s0 = esrc[t], s1 = esrc[t + 1];
    uint4 d0 = *(const uint4*)(zb + (size_t)s0 * 128 + l16 * 8);
    uint4 d1 = *(const uint4*)(zb + (size_t)s1 * 128 + l16 * 8);
    a0 += bf_lo(d0.x); a1 += bf_hi(d0.x);
    a2 += bf_lo(d0.y); a3 += bf_hi(d0.y);
    a4 += bf_lo(d0.z); a5 += bf_hi(d0.z);
    a6 += bf_lo(d0.w); a7 += bf_hi(d0.w);
    a0 += bf_lo(d1.x); a1 += bf_hi(d1.x);
    a2 += bf_lo(d1.y); a3 += bf_hi(d1.y);
    a4 += bf_lo(d1.z); a5 += bf_hi(d1.z);
    a6 += bf_lo(d1.w); a7 += bf_hi(d1.w);
  }
  if (t < end) {
    int s0 = esrc[t];
    uint4 d0 = *(const uint4*)(zb + (size_t)s0 * 128 + l16 * 8);
    a0 += bf_lo(d0.x); a1 += bf_hi(d0.x);
    a2 += bf_lo(d0.y); a3 += bf_hi(d0.y);
    a4 += bf_lo(d0.z); a5 += bf_hi(d0.z);
    a6 += bf_lo(d0.w); a7 += bf_hi(d0.w);
  }
  float ic = inv_cnt[node];
  unsigned* op = aggp + (size_t)node * 128 + l16 * 8;
  uint4 o0, o1;
  o0.x = pack_hl(a0 * ic); o0.y = pack_hl(a1 * ic);
  o0.z = pack_hl(a2 * ic); o0.w = pack_hl(a3 * ic);
  o1.x = pack_hl(a4 * ic); o1.y = pack_hl(a5 * ic);
  o1.z = pack_hl(a6 * ic); o1.w = pack_hl(a7 * ic);
  *(uint4*)op = o0;
  *(uint4*)(op + 4) = o1;
}

// ---------------- SAGE layer via MFMA ----------------
// A: k<128 from packed agg (hi/lo), k>=128 from zb (single bf16).
__global__ __launch_bounds__(256, 4) void sage_layer_mfma_k(
    const unsigned short* __restrict__ zb, const unsigned* __restrict__ aggp,
    const unsigned short* __restrict__ wf, const float* __restrict__ bl,
    unsigned short* __restrict__ out_bf, int n, int ntiles) {
  __shared__ unsigned short Ah_s[32 * 256];
  __shared__ unsigned short Al_s[32 * 128];
  __shared__ float psum[2][4][16];

  const int lane = threadIdx.x & 63;
  const int wv = threadIdx.x >> 6;
  const int g = lane >> 4;
  const int rl = lane & 15;

  const bf16x8* wfv = (const bf16x8*)wf;
  const int t0 = wv * 2, t1 = wv * 2 + 1;
  bf16x8 Bh0[8], Bh1[8], Bl0[8], Bl1[8];
#pragma unroll
  for (int c = 0; c < 8; ++c) {
    Bh0[c] = wfv[((0 * 8 + t0) * 8 + c) * 64 + lane];
    Bh1[c] = wfv[((0 * 8 + t1) * 8 + c) * 64 + lane];
    Bl0[c] = wfv[((1 * 8 + t0) * 8 + c) * 64 + lane];
    Bl1[c] = wfv[((1 * 8 + t1) * 8 + c) * 64 + lane];
  }
  const float b0 = bl[t0 * 16 + rl];
  const float b1 = bl[t1 * 16 + rl];

  char* pAh = (char*)Ah_s;
  char* pAl = (char*)Al_s;

  for (int tile = blockIdx.x; tile < ntiles; tile += gridDim.x) {
    const int v0 = tile * 32;

    // ---- stage agg rows (unpack packed hi|lo), k in [0,128)
#pragma unroll
    for (int q = 0; q < 4; ++q) {
      int lin = q * 1024 + threadIdx.x * 4;
      int r = lin >> 7;
      int col = lin & 127;
      int v = v0 + r; v = (v < n) ? v : (n - 1);
      uint4 p = *(const uint4*)(aggp + (size_t)v * 128 + col);
      uint2 hw, lw;
      hw.x = (p.x >> 16) | (p.y & 0xFFFF0000u);
      hw.y = (p.z >> 16) | (p.w & 0xFFFF0000u);
      lw.x = (p.x & 0xFFFFu) | (p.y << 16);
      lw.y = (p.z & 0xFFFFu) | (p.w << 16);
      int swz = (r & 7) << 4;
      *(uint2*)(pAh + ((r * 512 + col * 2) ^ swz)) = hw;
      *(uint2*)(pAl + ((r * 256 + col * 2) ^ swz)) = lw;
    }
    // ---- stage z rows (bf16 copy), k in [128,256)
#pragma unroll
    for (int q = 0; q < 2; ++q) {
      int lin = q * 2048 + threadIdx.x * 8;
      int r = lin >> 7;
      int col = lin & 127;
      int v = v0 + r; v = (v < n) ? v : (n - 1);
      uint4 d = *(const uint4*)(zb + (size_t)v * 128 + col);
      int byte = (r * 512 + 256 + col * 2) ^ ((r & 7) << 4);
      *(uint4*)(pAh + byte) = d;
    }
    __syncthreads();

#pragma unroll
    for (int s = 0; s < 2; ++s) {
      f32x4 a0 = {0.f, 0.f, 0.f, 0.f};
      f32x4 a1 = {0.f, 0.f, 0.f, 0.f};
      const int rowH = (s * 16 + rl) * 512;
      const int rowL = (s * 16 + rl) * 256;
      const int swz = (rl & 7) << 4;
#pragma unroll
      for (int c = 0; c < 4; ++c) {
        int offH = (rowH + c * 64 + g * 16) ^ swz;
        int offL = (rowL + c * 64 + g * 16) ^ swz;
        bf16x8 ah = *(const bf16x8*)(pAh + offH);
        bf16x8 al = *(const bf16x8*)(pAl + offL);
        a0 = MFMA16(ah, Bh0[c], a0); a1 = MFMA16(ah, Bh1[c], a1);
        a0 = MFMA16(ah, Bl0[c], a0); a1 = MFMA16(ah, Bl1[c], a1);
        a0 = MFMA16(al, Bh0[c], a0); a1 = MFMA16(al, Bh1[c], a1);
      }
#pragma unroll
      for (int c = 4; c < 8; ++c) {
        int offH = (rowH + c * 64 + g * 16) ^ swz;
        bf16x8 ah = *(const bf16x8*)(pAh + offH);
        a0 = MFMA16(ah, Bh0[c], a0); a1 = MFMA16(ah, Bh1[c], a1);
        a0 = MFMA16(ah, Bl0[c], a0); a1 = MFMA16(ah, Bl1[c], a1);
      }
      float pr[4];
#pragma unroll
      for (int j = 0; j < 4; ++j) {
        a0[j] += b0; a1[j] += b1;
        pr[j] = a0[j] * a0[j] + a1[j] * a1[j];
      }
#pragma unroll
      for (int m = 1; m < 16; m <<= 1) {
#pragma unroll
        for (int j = 0; j < 4; ++j) pr[j] += __shfl_xor(pr[j], m);
      }
      if (rl == 0) {
#pragma unroll
        for (int j = 0; j < 4; ++j) psum[s][wv][g * 4 + j] = pr[j];
      }
      __syncthreads();
#pragma unroll
      for (int j = 0; j < 4; ++j) {
        int row16 = g * 4 + j;
        float tot = psum[s][0][row16] + psum[s][1][row16] +
                    psum[s][2][row16] + psum[s][3][row16];
        float inv = 1.0f / fmaxf(sqrtf(tot), 1e-12f);
        int v = v0 + s * 16 + row16;
        if (v < n) {
          float o0 = fmaxf(a0[j] * inv, 0.f);
          float o1 = fmaxf(a1[j] * inv, 0.f);
          out_bf[(size_t)v * 128 + t0 * 16 + rl] = (unsigned short)rne_bf16(o0);
          out_bf[(size_t)v * 128 + t1 * 16 + rl] = (unsigned short)rne_bf16(o1);
        }
      }
    }
    __syncthreads();
  }
}

// ---------------- final linear via MFMA ----------------
__global__ __launch_bounds__(256, 4) void final_linear_mfma_k(
    const unsigned short* __restrict__ zb, const unsigned short* __restrict__ wlf,
    const float* __restrict__ blin, float* __restrict__ out, int n, int ntiles) {
  __shared__ unsigned short Az[64 * 128];

  const int lane = threadIdx.x & 63;
  const int wv = threadIdx.x >> 6;
  const int g = lane >> 4;
  const int rl = lane & 15;

  const bf16x8* wv8 = (const bf16x8*)wlf;
  bf16x8 B[3][4];
#pragma unroll
  for (int t = 0; t < 3; ++t)
#pragma unroll
    for (int c = 0; c < 4; ++c) B[t][c] = wv8[(t * 4 + c) * 64 + lane];
  float bias[3];
#pragma unroll
  for (int t = 0; t < 3; ++t) {
    int col = t * 16 + rl;
    bias[t] = (col < 40) ? blin[col] : 0.f;
  }

  char* pAz = (char*)Az;

  for (int tile = blockIdx.x; tile < ntiles; tile += gridDim.x) {
    const int v0 = tile * 64;
#pragma unroll
    for (int q = 0; q < 4; ++q) {
      int lin = q * 2048 + threadIdx.x * 8;
      int r = lin >> 7;
      int col = lin & 127;
      int v = v0 + r; v = (v < n) ? v : (n - 1);
      uint4 d = *(const uint4*)(zb + (size_t)v * 128 + col);
      int byte = (r * 256 + col * 2) ^ ((r & 7) << 4);
      *(uint4*)(pAz + byte) = d;
    }
    __syncthreads();

    f32x4 acc0 = {0.f, 0.f, 0.f, 0.f};
    f32x4 acc1 = {0.f, 0.f, 0.f, 0.f};
    f32x4 acc2 = {0.f, 0.f, 0.f, 0.f};
    const int rowB = (wv * 16 + rl) * 256;
    const int swz = (rl & 7) << 4;
#pragma unroll
    for (int c = 0; c < 4; ++c) {
      int off = (rowB + c * 64 + g * 16) ^ swz;
      bf16x8 a = *(const bf16x8*)(pAz + off);
      acc0 = MFMA16(a, B[0][c], acc0);
      acc1 = MFMA16(a, B[1][c], acc1);
      acc2 = MFMA16(a, B[2][c], acc2);
    }
#pragma unroll
    for (int j = 0; j < 4; ++j) {
      int v = v0 + wv * 16 + g * 4 + j;
      if (v < n) {
        float* op = out + (size_t)v * 40;
        op[rl] = acc0[j] + bias[0];
        op[16 + rl] = acc1[j] + bias[1];
        if (rl < 8) op[32 + rl] = acc2[j] + bias[2];
      }
    }
    __syncthreads();
  }
}

// ---------------- launch ----------------

extern "C" void kernel_launch(void* const* d_in, const int* in_sizes, int n_in,
                              void* d_out, int out_size, void* d_ws, size_t ws_size,
                              hipStream_t stream) {
  const float* x    = (const float*)d_in[0];
  const int*   ei   = (const int*)d_in[1];
  const float* Wl   = (const float*)d_in[2];
  const float* bl   = (const float*)d_in[3];
  const float* Wr   = (const float*)d_in[4];
  const float* Wlin = (const float*)d_in[5];
  const float* blin = (const float*)d_in[6];

  const int N = in_sizes[0] / 128;
  const int E = in_sizes[1] / 2;
  const int D = 128;
  const int NC = (N + 1023) >> 10;

  const int* src = ei;
  const int* dstp = ei + E;

  // workspace layout
  unsigned short* planeA = (unsigned short*)d_ws;            // N*128 bf16
  unsigned short* planeB = planeA + (size_t)N * D;           // N*128 bf16
  unsigned* aggp = (unsigned*)(planeB + (size_t)N * D);      // N*128 packed hi|lo
  float* inv_cnt = (float*)(aggp + (size_t)N * D);           // N
  unsigned short* wlf = (unsigned short*)(inv_cnt + N);      // 6144 ushorts
  unsigned short* Wfrag = wlf + 6144;                        // 3*65536
  int*   offsets = (int*)(Wfrag + 3 * 65536);                // N+1
  int*   esrc    = offsets + N + 1;                          // E
  unsigned* coarse = (unsigned*)(esrc + E);                  // E
  int*   cbase   = (int*)(coarse + E);                       // 129
  int*   gcur    = cbase + 129;                              // 128
  int*   ghist   = gcur + 128;                               // 128

  // CSR build
  hipMemsetAsync(ghist, 0, 128 * 4, stream);
  histA_k<<<(E + 2047) / 2048, 256, 0, stream>>>(dstp, ghist, E);
  cscan_k<<<1, 128, 0, stream>>>(ghist, cbase, gcur, E);
  bucketA_k<<<(E + 2047) / 2048, 256, 0, stream>>>(src, dstp, gcur, coarse, E, NC);
  bucketB_k<<<NC, 256, 0, stream>>>(cbase, coarse, esrc, offsets, inv_cnt, N, E);

  // weight prep + bf16 x plane
  wfrag_prep_k<<<96, 256, 0, stream>>>(Wl, Wr, Wfrag);
  wlin_frag_k<<<3, 256, 0, stream>>>(Wlin, wlf);
  to_bf16_k<<<((N * 32) + 255) / 256, 256, 0, stream>>>((const float4*)x, (uint2*)planeA, N * 32);

  const int aggGrid = (N * 16 + 255) / 256;   // 16 threads per node
  const int ntiles = (N + 31) / 32;
  const int sageGrid = 1024;

  // layer 1
  aggregate_k<<<aggGrid, 256, 0, stream>>>(planeA, offsets, esrc, inv_cnt, aggp, N);
  sage_layer_mfma_k<<<sageGrid, 256, 0, stream>>>(planeA, aggp, Wfrag + 0 * 65536, bl + 0 * D, planeB, N, ntiles);
  // layer 2
  aggregate_k<<<aggGrid, 256, 0, stream>>>(planeB, offsets, esrc, inv_cnt, aggp, N);
  sage_layer_mfma_k<<<sageGrid, 256, 0, stream>>>(planeB, aggp, Wfrag + 1 * 65536, bl + 1 * D, planeA, N, ntiles);
  // layer 3
  aggregate_k<<<aggGrid, 256, 0, stream>>>(planeA, offsets, esrc, inv_cnt, aggp, N);
  sage_layer_mfma_k<<<sageGrid, 256, 0, stream>>>(planeA, aggp, Wfrag + 2 * 65536, bl + 2 * D, planeB, N, ntiles);

  // final linear (MFMA)
  const int ntiles64 = (N + 63) / 64;
  final_linear_mfma_k<<<ntiles64, 256, 0, stream>>>(planeB, wlf, blin, (float*)d_out, N, ntiles64);
}

// Round 9
// 436.491 us; speedup vs baseline: 1.4397x; 1.4397x over previous
//
#include <hip/hip_runtime.h>

// ---------------------------------------------------------------------------
// GraphSAGE 3-layer forward.
//   CSR build (coarse-hist + two-pass LDS bucket) -> bf16 planes -> per-layer:
//   aggregate(mean, quarter-wave-per-node, packed hi|lo bf16 out)
//   -> MFMA GEMM [agg(hi/lo)|z(bf16)]@[Wl;Wr]^T + bias + L2norm + relu
//   -> final linear (MFMA).
// NOTE: sage needs 128 VGPR for resident B-fragments -> do NOT cap VGPRs via
// launch_bounds min-waves (R8 regression: spills -> 3x HBM traffic).
// Occupancy comes from grid = ntiles (4 blocks/CU at 128 VGPR / 25KB LDS).
// ---------------------------------------------------------------------------

typedef __bf16 bf16x8 __attribute__((ext_vector_type(8)));
typedef float  f32x4  __attribute__((ext_vector_type(4)));

#define MFMA16(a, b, c) __builtin_amdgcn_mfma_f32_16x16x32_bf16((a), (b), (c), 0, 0, 0)

__device__ __forceinline__ unsigned rne_bf16(float f) {
  unsigned u = __float_as_uint(f);
  unsigned r = u + 0x7FFFu + ((u >> 16) & 1u);
  return r >> 16;
}

__device__ __forceinline__ float bf_lo(unsigned u) { return __uint_as_float(u << 16); }
__device__ __forceinline__ float bf_hi(unsigned u) { return __uint_as_float(u & 0xFFFF0000u); }

// pack fp32 -> (hi bf16 <<16) | lo bf16
__device__ __forceinline__ unsigned pack_hl(float f) {
  unsigned h = rne_bf16(f);
  unsigned l = rne_bf16(f - __uint_as_float(h << 16));
  return (h << 16) | l;
}

// ---------------- CSR build ----------------
// pack = src | ((dst & 1023) << 17); requires N < 2^17, N/1024 <= 128.

__global__ __launch_bounds__(256) void histA_k(const int* __restrict__ dst,
                                               int* __restrict__ ghist, int E) {
  __shared__ int h[128];
  const int tid = threadIdx.x;
  if (tid < 128) h[tid] = 0;
  __syncthreads();
  const int e0 = blockIdx.x * 2048;
#pragma unroll
  for (int j = 0; j < 8; ++j) {
    int e = e0 + j * 256 + tid;
    if (e < E) atomicAdd(&h[dst[e] >> 10], 1);
  }
  __syncthreads();
  if (tid < 128 && h[tid]) atomicAdd(&ghist[tid], h[tid]);
}

__global__ void cscan_k(const int* __restrict__ ghist, int* __restrict__ cbase,
                        int* __restrict__ gcur, int E) {
  __shared__ int sd[128];
  const int tid = threadIdx.x;
  int v = ghist[tid];
  sd[tid] = v;
  __syncthreads();
  for (int off = 1; off < 128; off <<= 1) {
    int u = (tid >= off) ? sd[tid - off] : 0;
    __syncthreads();
    sd[tid] += u;
    __syncthreads();
  }
  int excl = sd[tid] - v;
  cbase[tid] = excl;
  gcur[tid] = excl;
  if (tid == 127) cbase[128] = sd[127];
}

__global__ __launch_bounds__(256) void bucketA_k(
    const int* __restrict__ src, const int* __restrict__ dst,
    int* __restrict__ gcur, unsigned* __restrict__ coarse, int E, int nc) {
  __shared__ int hist[128];
  __shared__ int sd[128];
  __shared__ int lpos[128];
  __shared__ int gbase[128];
  __shared__ unsigned stage[2048];
  __shared__ unsigned char sbuck[2048];

  const int tid = threadIdx.x;
  const int e0 = blockIdx.x * 2048;

  if (tid < 128) hist[tid] = 0;
  __syncthreads();

  int bv[8], pk[8];
#pragma unroll
  for (int j = 0; j < 8; ++j) {
    int e = e0 + j * 256 + tid;
    bv[j] = -1;
    if (e < E) {
      int s = src[e], d = dst[e];
      bv[j] = d >> 10;
      pk[j] = s | ((d & 1023) << 17);
      atomicAdd(&hist[bv[j]], 1);
    }
  }
  __syncthreads();

  if (tid < 128) sd[tid] = hist[tid];
  __syncthreads();
  for (int off = 1; off < 128; off <<= 1) {
    int t = 0;
    if (tid < 128 && tid >= off) t = sd[tid - off];
    __syncthreads();
    if (tid < 128) sd[tid] += t;
    __syncthreads();
  }
  if (tid < 128) {
    int excl = sd[tid] - hist[tid];
    lpos[tid] = excl;
    gbase[tid] = (tid < nc && hist[tid] > 0) ? atomicAdd(&gcur[tid], hist[tid]) : 0;
  }
  __syncthreads();

#pragma unroll
  for (int j = 0; j < 8; ++j) {
    if (bv[j] >= 0) {
      int slot = atomicAdd(&lpos[bv[j]], 1);
      stage[slot] = (unsigned)pk[j];
      sbuck[slot] = (unsigned char)bv[j];
    }
  }
  __syncthreads();

  const int total = sd[127];
  for (int i = tid; i < total; i += 256) {
    int b = sbuck[i];
    int excl = sd[b] - hist[b];
    coarse[gbase[b] + (i - excl)] = stage[i];
  }
}

__global__ __launch_bounds__(256) void bucketB_k(
    const int* __restrict__ cbase, const unsigned* __restrict__ coarse,
    int* __restrict__ esrc, int* __restrict__ offsets,
    float* __restrict__ inv_cnt, int n, int E) {
  __shared__ int hcnt[1024];
  __shared__ int cur[1024];
  __shared__ int sd[256];

  const int tid = threadIdx.x;
  const int b = blockIdx.x;
  const int base = b * 1024;
  const int nn = (n - base < 1024) ? (n - base) : 1024;
  const int cbeg = cbase[b];
  const int cend = cbase[b + 1];

  for (int j = tid; j < 1024; j += 256) hcnt[j] = 0;
  __syncthreads();
  for (int idx = cbeg + tid; idx < cend; idx += 256)
    atomicAdd(&hcnt[coarse[idx] >> 17], 1);
  __syncthreads();

  int b0 = hcnt[tid * 4], b1 = hcnt[tid * 4 + 1];
  int b2 = hcnt[tid * 4 + 2], b3 = hcnt[tid * 4 + 3];
  int tot = b0 + b1 + b2 + b3;
  sd[tid] = tot;
  __syncthreads();
  for (int off = 1; off < 256; off <<= 1) {
    int u = (tid >= off) ? sd[tid - off] : 0;
    __syncthreads();
    sd[tid] += u;
    __syncthreads();
  }
  int excl = cbeg + sd[tid] - tot;
  cur[tid * 4]     = excl;
  cur[tid * 4 + 1] = excl + b0;
  cur[tid * 4 + 2] = excl + b0 + b1;
  cur[tid * 4 + 3] = excl + b0 + b1 + b2;
  __syncthreads();

  for (int j = tid; j < nn; j += 256) {
    offsets[base + j] = cur[j];
    int c = hcnt[j] > 1 ? hcnt[j] : 1;
    inv_cnt[base + j] = 1.0f / (float)c;
  }
  if (tid == 0 && base + nn >= n) offsets[n] = cend;
  __syncthreads();

  for (int idx = cbeg + tid; idx < cend; idx += 256) {
    unsigned p = coarse[idx];
    int pos = atomicAdd(&cur[p >> 17], 1);
    esrc[pos] = (int)(p & 0x1FFFFu);
  }
}

// ---------------- fp32 -> bf16 plane ----------------
__global__ void to_bf16_k(const float4* __restrict__ in, uint2* __restrict__ out, int n4) {
  int i = blockIdx.x * 256 + threadIdx.x;
  if (i >= n4) return;
  float4 f = in[i];
  uint2 o;
  o.x = rne_bf16(f.x) | (rne_bf16(f.y) << 16);
  o.y = rne_bf16(f.z) | (rne_bf16(f.w) << 16);
  out[i] = o;
}

// ---------------- weight fragment prep (hi/lo bf16, MFMA B-layout) ----------
__global__ void wfrag_prep_k(const float* __restrict__ Wl, const float* __restrict__ Wr,
                             unsigned short* __restrict__ wfrag) {
  int id = blockIdx.x * 256 + threadIdx.x;
  if (id >= 3 * 2 * 8 * 8 * 64) return;
  int l = id & 63;
  int c = (id >> 6) & 7;
  int t = (id >> 9) & 7;
  int p = (id >> 12) & 1;
  int layer = id >> 13;
  int col = t * 16 + (l & 15);
  int kbase = c * 32 + (l >> 4) * 8;
  unsigned short* dst = wfrag + (size_t)layer * 65536 +
                        ((((size_t)p * 8 + t) * 8 + c) * 64 + l) * 8;
#pragma unroll
  for (int j = 0; j < 8; ++j) {
    int k = kbase + j;
    float w = (k < 128) ? Wl[layer * 16384 + col * 128 + k]
                        : Wr[layer * 16384 + col * 128 + (k - 128)];
    unsigned h = rne_bf16(w);
    unsigned o;
    if (p == 0) o = h;
    else o = rne_bf16(w - __uint_as_float(h << 16));
    dst[j] = (unsigned short)o;
  }
}

__global__ void wlin_frag_k(const float* __restrict__ Wlin, unsigned short* __restrict__ wlf) {
  int id = blockIdx.x * 256 + threadIdx.x;
  if (id >= 3 * 4 * 64) return;
  int l = id & 63;
  int c = (id >> 6) & 3;
  int t = id >> 8;
  int col = t * 16 + (l & 15);
  int kbase = c * 32 + (l >> 4) * 8;
  unsigned short* dst = wlf + (size_t)id * 8;
#pragma unroll
  for (int j = 0; j < 8; ++j) {
    float w = (col < 40) ? Wlin[col * 128 + kbase + j] : 0.f;
    dst[j] = (unsigned short)rne_bf16(w);
  }
}

// ---------------- aggregation: quarter-wave (16 lanes) per node ------------
__global__ void aggregate_k(const unsigned short* __restrict__ zb,
                            const int* __restrict__ offsets,
                            const int* __restrict__ esrc,
                            const float* __restrict__ inv_cnt,
                            unsigned* __restrict__ aggp, int n) {
  int node = (blockIdx.x * 256 + threadIdx.x) >> 4;
  int l16 = threadIdx.x & 15;
  if (node >= n) return;
  int beg = offsets[node], end = offsets[node + 1];
  float a0 = 0.f, a1 = 0.f, a2 = 0.f, a3 = 0.f;
  float a4 = 0.f, a5 = 0.f, a6 = 0.f, a7 = 0.f;
  int t = beg;
  for (; t + 2 <= end; t += 2) {
    int s0 = esrc[t], s1 = esrc[t + 1];
    uint4 d0 = *(const uint4*)(zb + (size_t)s0 * 128 + l16 * 8);
    uint4 d1 = *(const uint4*)(zb + (size_t)s1 * 128 + l16 * 8);
    a0 += bf_lo(d0.x); a1 += bf_hi(d0.x);
    a2 += bf_lo(d0.y); a3 += bf_hi(d0.y);
    a4 += bf_lo(d0.z); a5 += bf_hi(d0.z);
    a6 += bf_lo(d0.w); a7 += bf_hi(d0.w);
    a0 += bf_lo(d1.x); a1 += bf_hi(d1.x);
    a2 += bf_lo(d1.y); a3 += bf_hi(d1.y);
    a4 += bf_lo(d1.z); a5 += bf_hi(d1.z);
    a6 += bf_lo(d1.w); a7 += bf_hi(d1.w);
  }
  if (t < end) {
    int s0 = esrc[t];
    uint4 d0 = *(const uint4*)(zb + (size_t)s0 * 128 + l16 * 8);
    a0 += bf_lo(d0.x); a1 += bf_hi(d0.x);
    a2 += bf_lo(d0.y); a3 += bf_hi(d0.y);
    a4 += bf_lo(d0.z); a5 += bf_hi(d0.z);
    a6 += bf_lo(d0.w); a7 += bf_hi(d0.w);
  }
  float ic = inv_cnt[node];
  unsigned* op = aggp + (size_t)node * 128 + l16 * 8;
  uint4 o0, o1;
  o0.x = pack_hl(a0 * ic); o0.y = pack_hl(a1 * ic);
  o0.z = pack_hl(a2 * ic); o0.w = pack_hl(a3 * ic);
  o1.x = pack_hl(a4 * ic); o1.y = pack_hl(a5 * ic);
  o1.z = pack_hl(a6 * ic); o1.w = pack_hl(a7 * ic);
  *(uint4*)op = o0;
  *(uint4*)(op + 4) = o1;
}

// ---------------- SAGE layer via MFMA ----------------
// A: k<128 from packed agg (hi/lo), k>=128 from zb (single bf16).
// 128 VGPRs of B-fragments resident -> no min-waves launch bound.
__global__ __launch_bounds__(256) void sage_layer_mfma_k(
    const unsigned short* __restrict__ zb, const unsigned* __restrict__ aggp,
    const unsigned short* __restrict__ wf, const float* __restrict__ bl,
    unsigned short* __restrict__ out_bf, int n, int ntiles) {
  __shared__ unsigned short Ah_s[32 * 256];
  __shared__ unsigned short Al_s[32 * 128];
  __shared__ float psum[2][4][16];

  const int lane = threadIdx.x & 63;
  const int wv = threadIdx.x >> 6;
  const int g = lane >> 4;
  const int rl = lane & 15;

  const bf16x8* wfv = (const bf16x8*)wf;
  const int t0 = wv * 2, t1 = wv * 2 + 1;
  bf16x8 Bh0[8], Bh1[8], Bl0[8], Bl1[8];
#pragma unroll
  for (int c = 0; c < 8; ++c) {
    Bh0[c] = wfv[((0 * 8 + t0) * 8 + c) * 64 + lane];
    Bh1[c] = wfv[((0 * 8 + t1) * 8 + c) * 64 + lane];
    Bl0[c] = wfv[((1 * 8 + t0) * 8 + c) * 64 + lane];
    Bl1[c] = wfv[((1 * 8 + t1) * 8 + c) * 64 + lane];
  }
  const float b0 = bl[t0 * 16 + rl];
  const float b1 = bl[t1 * 16 + rl];

  char* pAh = (char*)Ah_s;
  char* pAl = (char*)Al_s;

  for (int tile = blockIdx.x; tile < ntiles; tile += gridDim.x) {
    const int v0 = tile * 32;

    // ---- stage agg rows (unpack packed hi|lo), k in [0,128)
#pragma unroll
    for (int q = 0; q < 4; ++q) {
      int lin = q * 1024 + threadIdx.x * 4;
      int r = lin >> 7;
      int col = lin & 127;
      int v = v0 + r; v = (v < n) ? v : (n - 1);
      uint4 p = *(const uint4*)(aggp + (size_t)v * 128 + col);
      uint2 hw, lw;
      hw.x = (p.x >> 16) | (p.y & 0xFFFF0000u);
      hw.y = (p.z >> 16) | (p.w & 0xFFFF0000u);
      lw.x = (p.x & 0xFFFFu) | (p.y << 16);
      lw.y = (p.z & 0xFFFFu) | (p.w << 16);
      int swz = (r & 7) << 4;
      *(uint2*)(pAh + ((r * 512 + col * 2) ^ swz)) = hw;
      *(uint2*)(pAl + ((r * 256 + col * 2) ^ swz)) = lw;
    }
    // ---- stage z rows (bf16 copy), k in [128,256)
#pragma unroll
    for (int q = 0; q < 2; ++q) {
      int lin = q * 2048 + threadIdx.x * 8;
      int r = lin >> 7;
      int col = lin & 127;
      int v = v0 + r; v = (v < n) ? v : (n - 1);
      uint4 d = *(const uint4*)(zb + (size_t)v * 128 + col);
      int byte = (r * 512 + 256 + col * 2) ^ ((r & 7) << 4);
      *(uint4*)(pAh + byte) = d;
    }
    __syncthreads();

#pragma unroll
    for (int s = 0; s < 2; ++s) {
      f32x4 a0 = {0.f, 0.f, 0.f, 0.f};
      f32x4 a1 = {0.f, 0.f, 0.f, 0.f};
      const int rowH = (s * 16 + rl) * 512;
      const int rowL = (s * 16 + rl) * 256;
      const int swz = (rl & 7) << 4;
#pragma unroll
      for (int c = 0; c < 4; ++c) {
        int offH = (rowH + c * 64 + g * 16) ^ swz;
        int offL = (rowL + c * 64 + g * 16) ^ swz;
        bf16x8 ah = *(const bf16x8*)(pAh + offH);
        bf16x8 al = *(const bf16x8*)(pAl + offL);
        a0 = MFMA16(ah, Bh0[c], a0); a1 = MFMA16(ah, Bh1[c], a1);
        a0 = MFMA16(ah, Bl0[c], a0); a1 = MFMA16(ah, Bl1[c], a1);
        a0 = MFMA16(al, Bh0[c], a0); a1 = MFMA16(al, Bh1[c], a1);
      }
#pragma unroll
      for (int c = 4; c < 8; ++c) {
        int offH = (rowH + c * 64 + g * 16) ^ swz;
        bf16x8 ah = *(const bf16x8*)(pAh + offH);
        a0 = MFMA16(ah, Bh0[c], a0); a1 = MFMA16(ah, Bh1[c], a1);
        a0 = MFMA16(ah, Bl0[c], a0); a1 = MFMA16(ah, Bl1[c], a1);
      }
      float pr[4];
#pragma unroll
      for (int j = 0; j < 4; ++j) {
        a0[j] += b0; a1[j] += b1;
        pr[j] = a0[j] * a0[j] + a1[j] * a1[j];
      }
#pragma unroll
      for (int m = 1; m < 16; m <<= 1) {
#pragma unroll
        for (int j = 0; j < 4; ++j) pr[j] += __shfl_xor(pr[j], m);
      }
      if (rl == 0) {
#pragma unroll
        for (int j = 0; j < 4; ++j) psum[s][wv][g * 4 + j] = pr[j];
      }
      __syncthreads();
#pragma unroll
      for (int j = 0; j < 4; ++j) {
        int row16 = g * 4 + j;
        float tot = psum[s][0][row16] + psum[s][1][row16] +
                    psum[s][2][row16] + psum[s][3][row16];
        float inv = 1.0f / fmaxf(sqrtf(tot), 1e-12f);
        int v = v0 + s * 16 + row16;
        if (v < n) {
          float o0 = fmaxf(a0[j] * inv, 0.f);
          float o1 = fmaxf(a1[j] * inv, 0.f);
          out_bf[(size_t)v * 128 + t0 * 16 + rl] = (unsigned short)rne_bf16(o0);
          out_bf[(size_t)v * 128 + t1 * 16 + rl] = (unsigned short)rne_bf16(o1);
        }
      }
    }
    __syncthreads();
  }
}

// ---------------- final linear via MFMA ----------------
__global__ __launch_bounds__(256, 4) void final_linear_mfma_k(
    const unsigned short* __restrict__ zb, const unsigned short* __restrict__ wlf,
    const float* __restrict__ blin, float* __restrict__ out, int n, int ntiles) {
  __shared__ unsigned short Az[64 * 128];

  const int lane = threadIdx.x & 63;
  const int wv = threadIdx.x >> 6;
  const int g = lane >> 4;
  const int rl = lane & 15;

  const bf16x8* wv8 = (const bf16x8*)wlf;
  bf16x8 B[3][4];
#pragma unroll
  for (int t = 0; t < 3; ++t)
#pragma unroll
    for (int c = 0; c < 4; ++c) B[t][c] = wv8[(t * 4 + c) * 64 + lane];
  float bias[3];
#pragma unroll
  for (int t = 0; t < 3; ++t) {
    int col = t * 16 + rl;
    bias[t] = (col < 40) ? blin[col] : 0.f;
  }

  char* pAz = (char*)Az;

  for (int tile = blockIdx.x; tile < ntiles; tile += gridDim.x) {
    const int v0 = tile * 64;
#pragma unroll
    for (int q = 0; q < 4; ++q) {
      int lin = q * 2048 + threadIdx.x * 8;
      int r = lin >> 7;
      int col = lin & 127;
      int v = v0 + r; v = (v < n) ? v : (n - 1);
      uint4 d = *(const uint4*)(zb + (size_t)v * 128 + col);
      int byte = (r * 256 + col * 2) ^ ((r & 7) << 4);
      *(uint4*)(pAz + byte) = d;
    }
    __syncthreads();

    f32x4 acc0 = {0.f, 0.f, 0.f, 0.f};
    f32x4 acc1 = {0.f, 0.f, 0.f, 0.f};
    f32x4 acc2 = {0.f, 0.f, 0.f, 0.f};
    const int rowB = (wv * 16 + rl) * 256;
    const int swz = (rl & 7) << 4;
#pragma unroll
    for (int c = 0; c < 4; ++c) {
      int off = (rowB + c * 64 + g * 16) ^ swz;
      bf16x8 a = *(const bf16x8*)(pAz + off);
      acc0 = MFMA16(a, B[0][c], acc0);
      acc1 = MFMA16(a, B[1][c], acc1);
      acc2 = MFMA16(a, B[2][c], acc2);
    }
#pragma unroll
    for (int j = 0; j < 4; ++j) {
      int v = v0 + wv * 16 + g * 4 + j;
      if (v < n) {
        float* op = out + (size_t)v * 40;
        op[rl] = acc0[j] + bias[0];
        op[16 + rl] = acc1[j] + bias[1];
        if (rl < 8) op[32 + rl] = acc2[j] + bias[2];
      }
    }
    __syncthreads();
  }
}

// ---------------- launch ----------------

extern "C" void kernel_launch(void* const* d_in, const int* in_sizes, int n_in,
                              void* d_out, int out_size, void* d_ws, size_t ws_size,
                              hipStream_t stream) {
  const float* x    = (const float*)d_in[0];
  const int*   ei   = (const int*)d_in[1];
  const float* Wl   = (const float*)d_in[2];
  const float* bl   = (const float*)d_in[3];
  const float* Wr   = (const float*)d_in[4];
  const float* Wlin = (const float*)d_in[5];
  const float* blin = (const float*)d_in[6];

  const int N = in_sizes[0] / 128;
  const int E = in_sizes[1] / 2;
  const int D = 128;
  const int NC = (N + 1023) >> 10;

  const int* src = ei;
  const int* dstp = ei + E;

  // workspace layout
  unsigned short* planeA = (unsigned short*)d_ws;            // N*128 bf16
  unsigned short* planeB = planeA + (size_t)N * D;           // N*128 bf16
  unsigned* aggp = (unsigned*)(planeB + (size_t)N * D);      // N*128 packed hi|lo
  float* inv_cnt = (float*)(aggp + (size_t)N * D);           // N
  unsigned short* wlf = (unsigned short*)(inv_cnt + N);      // 6144 ushorts
  unsigned short* Wfrag = wlf + 6144;                        // 3*65536
  int*   offsets = (int*)(Wfrag + 3 * 65536);                // N+1
  int*   esrc    = offsets + N + 1;                          // E
  unsigned* coarse = (unsigned*)(esrc + E);                  // E
  int*   cbase   = (int*)(coarse + E);                       // 129
  int*   gcur    = cbase + 129;                              // 128
  int*   ghist   = gcur + 128;                               // 128

  // CSR build
  hipMemsetAsync(ghist, 0, 128 * 4, stream);
  histA_k<<<(E + 2047) / 2048, 256, 0, stream>>>(dstp, ghist, E);
  cscan_k<<<1, 128, 0, stream>>>(ghist, cbase, gcur, E);
  bucketA_k<<<(E + 2047) / 2048, 256, 0, stream>>>(src, dstp, gcur, coarse, E, NC);
  bucketB_k<<<NC, 256, 0, stream>>>(cbase, coarse, esrc, offsets, inv_cnt, N, E);

  // weight prep + bf16 x plane
  wfrag_prep_k<<<96, 256, 0, stream>>>(Wl, Wr, Wfrag);
  wlin_frag_k<<<3, 256, 0, stream>>>(Wlin, wlf);
  to_bf16_k<<<((N * 32) + 255) / 256, 256, 0, stream>>>((const float4*)x, (uint2*)planeA, N * 32);

  const int aggGrid = (N * 16 + 255) / 256;   // 16 threads per node
  const int ntiles = (N + 31) / 32;

  // layer 1
  aggregate_k<<<aggGrid, 256, 0, stream>>>(planeA, offsets, esrc, inv_cnt, aggp, N);
  sage_layer_mfma_k<<<ntiles, 256, 0, stream>>>(planeA, aggp, Wfrag + 0 * 65536, bl + 0 * D, planeB, N, ntiles);
  // layer 2
  aggregate_k<<<aggGrid, 256, 0, stream>>>(planeB, offsets, esrc, inv_cnt, aggp, N);
  sage_layer_mfma_k<<<ntiles, 256, 0, stream>>>(planeB, aggp, Wfrag + 1 * 65536, bl + 1 * D, planeA, N, ntiles);
  // layer 3
  aggregate_k<<<aggGrid, 256, 0, stream>>>(planeA, offsets, esrc, inv_cnt, aggp, N);
  sage_layer_mfma_k<<<ntiles, 256, 0, stream>>>(planeA, aggp, Wfrag + 2 * 65536, bl + 2 * D, planeB, N, ntiles);

  // final linear (MFMA)
  const int ntiles64 = (N + 63) / 64;
  final_linear_mfma_k<<<ntiles64, 256, 0, stream>>>(planeB, wlf, blin, (float*)d_out, N, ntiles64);
}

// Round 10
// 425.735 us; speedup vs baseline: 1.4760x; 1.0253x over previous
//
#include <hip/hip_runtime.h>

// ---------------------------------------------------------------------------
// GraphSAGE 3-layer forward.
//   CSR build (coarse-hist + two-pass LDS bucket) -> bf16 planes -> per-layer:
//   aggregate(mean, quarter-wave/node, 4-deep MLP, separate hi/lo planes)
//   -> MFMA GEMM [agg(hi/lo)|z(bf16)]@[Wl;Wr]^T + bias + L2norm + relu
//   -> final linear (MFMA).
// NOTE: sage needs 128 VGPR resident B-fragments -> no min-waves launch bound
// (R8: VGPR cap -> spills -> 3x HBM). Occupancy via grid = ntiles.
// ---------------------------------------------------------------------------

typedef __bf16 bf16x8 __attribute__((ext_vector_type(8)));
typedef float  f32x4  __attribute__((ext_vector_type(4)));

#define MFMA16(a, b, c) __builtin_amdgcn_mfma_f32_16x16x32_bf16((a), (b), (c), 0, 0, 0)

__device__ __forceinline__ unsigned rne_bf16(float f) {
  unsigned u = __float_as_uint(f);
  unsigned r = u + 0x7FFFu + ((u >> 16) & 1u);
  return r >> 16;
}

__device__ __forceinline__ float bf_lo(unsigned u) { return __uint_as_float(u << 16); }
__device__ __forceinline__ float bf_hi(unsigned u) { return __uint_as_float(u & 0xFFFF0000u); }

// ---------------- CSR build ----------------
// pack = src | ((dst & 1023) << 17); requires N < 2^17, N/1024 <= 128.

__global__ __launch_bounds__(256) void histA_k(const int* __restrict__ dst,
                                               int* __restrict__ ghist, int E) {
  __shared__ int h[128];
  const int tid = threadIdx.x;
  if (tid < 128) h[tid] = 0;
  __syncthreads();
  const int e0 = blockIdx.x * 2048;
#pragma unroll
  for (int j = 0; j < 8; ++j) {
    int e = e0 + j * 256 + tid;
    if (e < E) atomicAdd(&h[dst[e] >> 10], 1);
  }
  __syncthreads();
  if (tid < 128 && h[tid]) atomicAdd(&ghist[tid], h[tid]);
}

__global__ void cscan_k(const int* __restrict__ ghist, int* __restrict__ cbase,
                        int* __restrict__ gcur, int E) {
  __shared__ int sd[128];
  const int tid = threadIdx.x;
  int v = ghist[tid];
  sd[tid] = v;
  __syncthreads();
  for (int off = 1; off < 128; off <<= 1) {
    int u = (tid >= off) ? sd[tid - off] : 0;
    __syncthreads();
    sd[tid] += u;
    __syncthreads();
  }
  int excl = sd[tid] - v;
  cbase[tid] = excl;
  gcur[tid] = excl;
  if (tid == 127) cbase[128] = sd[127];
}

__global__ __launch_bounds__(256) void bucketA_k(
    const int* __restrict__ src, const int* __restrict__ dst,
    int* __restrict__ gcur, unsigned* __restrict__ coarse, int E, int nc) {
  __shared__ int hist[128];
  __shared__ int sd[128];
  __shared__ int lpos[128];
  __shared__ int gbase[128];
  __shared__ unsigned stage[2048];
  __shared__ unsigned char sbuck[2048];

  const int tid = threadIdx.x;
  const int e0 = blockIdx.x * 2048;

  if (tid < 128) hist[tid] = 0;
  __syncthreads();

  int bv[8], pk[8];
#pragma unroll
  for (int j = 0; j < 8; ++j) {
    int e = e0 + j * 256 + tid;
    bv[j] = -1;
    if (e < E) {
      int s = src[e], d = dst[e];
      bv[j] = d >> 10;
      pk[j] = s | ((d & 1023) << 17);
      atomicAdd(&hist[bv[j]], 1);
    }
  }
  __syncthreads();

  if (tid < 128) sd[tid] = hist[tid];
  __syncthreads();
  for (int off = 1; off < 128; off <<= 1) {
    int t = 0;
    if (tid < 128 && tid >= off) t = sd[tid - off];
    __syncthreads();
    if (tid < 128) sd[tid] += t;
    __syncthreads();
  }
  if (tid < 128) {
    int excl = sd[tid] - hist[tid];
    lpos[tid] = excl;
    gbase[tid] = (tid < nc && hist[tid] > 0) ? atomicAdd(&gcur[tid], hist[tid]) : 0;
  }
  __syncthreads();

#pragma unroll
  for (int j = 0; j < 8; ++j) {
    if (bv[j] >= 0) {
      int slot = atomicAdd(&lpos[bv[j]], 1);
      stage[slot] = (unsigned)pk[j];
      sbuck[slot] = (unsigned char)bv[j];
    }
  }
  __syncthreads();

  const int total = sd[127];
  for (int i = tid; i < total; i += 256) {
    int b = sbuck[i];
    int excl = sd[b] - hist[b];
    coarse[gbase[b] + (i - excl)] = stage[i];
  }
}

__global__ __launch_bounds__(256) void bucketB_k(
    const int* __restrict__ cbase, const unsigned* __restrict__ coarse,
    int* __restrict__ esrc, int* __restrict__ offsets,
    float* __restrict__ inv_cnt, int n, int E) {
  __shared__ int hcnt[1024];
  __shared__ int cur[1024];
  __shared__ int sd[256];

  const int tid = threadIdx.x;
  const int b = blockIdx.x;
  const int base = b * 1024;
  const int nn = (n - base < 1024) ? (n - base) : 1024;
  const int cbeg = cbase[b];
  const int cend = cbase[b + 1];

  for (int j = tid; j < 1024; j += 256) hcnt[j] = 0;
  __syncthreads();
  for (int idx = cbeg + tid; idx < cend; idx += 256)
    atomicAdd(&hcnt[coarse[idx] >> 17], 1);
  __syncthreads();

  int b0 = hcnt[tid * 4], b1 = hcnt[tid * 4 + 1];
  int b2 = hcnt[tid * 4 + 2], b3 = hcnt[tid * 4 + 3];
  int tot = b0 + b1 + b2 + b3;
  sd[tid] = tot;
  __syncthreads();
  for (int off = 1; off < 256; off <<= 1) {
    int u = (tid >= off) ? sd[tid - off] : 0;
    __syncthreads();
    sd[tid] += u;
    __syncthreads();
  }
  int excl = cbeg + sd[tid] - tot;
  cur[tid * 4]     = excl;
  cur[tid * 4 + 1] = excl + b0;
  cur[tid * 4 + 2] = excl + b0 + b1;
  cur[tid * 4 + 3] = excl + b0 + b1 + b2;
  __syncthreads();

  for (int j = tid; j < nn; j += 256) {
    offsets[base + j] = cur[j];
    int c = hcnt[j] > 1 ? hcnt[j] : 1;
    inv_cnt[base + j] = 1.0f / (float)c;
  }
  if (tid == 0 && base + nn >= n) offsets[n] = cend;
  __syncthreads();

  for (int idx = cbeg + tid; idx < cend; idx += 256) {
    unsigned p = coarse[idx];
    int pos = atomicAdd(&cur[p >> 17], 1);
    esrc[pos] = (int)(p & 0x1FFFFu);
  }
}

// ---------------- fp32 -> bf16 plane ----------------
__global__ void to_bf16_k(const float4* __restrict__ in, uint2* __restrict__ out, int n4) {
  int i = blockIdx.x * 256 + threadIdx.x;
  if (i >= n4) return;
  float4 f = in[i];
  uint2 o;
  o.x = rne_bf16(f.x) | (rne_bf16(f.y) << 16);
  o.y = rne_bf16(f.z) | (rne_bf16(f.w) << 16);
  out[i] = o;
}

// ---------------- weight fragment prep (hi/lo bf16, MFMA B-layout) ----------
__global__ void wfrag_prep_k(const float* __restrict__ Wl, const float* __restrict__ Wr,
                             unsigned short* __restrict__ wfrag) {
  int id = blockIdx.x * 256 + threadIdx.x;
  if (id >= 3 * 2 * 8 * 8 * 64) return;
  int l = id & 63;
  int c = (id >> 6) & 7;
  int t = (id >> 9) & 7;
  int p = (id >> 12) & 1;
  int layer = id >> 13;
  int col = t * 16 + (l & 15);
  int kbase = c * 32 + (l >> 4) * 8;
  unsigned short* dst = wfrag + (size_t)layer * 65536 +
                        ((((size_t)p * 8 + t) * 8 + c) * 64 + l) * 8;
#pragma unroll
  for (int j = 0; j < 8; ++j) {
    int k = kbase + j;
    float w = (k < 128) ? Wl[layer * 16384 + col * 128 + k]
                        : Wr[layer * 16384 + col * 128 + (k - 128)];
    unsigned h = rne_bf16(w);
    unsigned o;
    if (p == 0) o = h;
    else o = rne_bf16(w - __uint_as_float(h << 16));
    dst[j] = (unsigned short)o;
  }
}

__global__ void wlin_frag_k(const float* __restrict__ Wlin, unsigned short* __restrict__ wlf) {
  int id = blockIdx.x * 256 + threadIdx.x;
  if (id >= 3 * 4 * 64) return;
  int l = id & 63;
  int c = (id >> 6) & 3;
  int t = id >> 8;
  int col = t * 16 + (l & 15);
  int kbase = c * 32 + (l >> 4) * 8;
  unsigned short* dst = wlf + (size_t)id * 8;
#pragma unroll
  for (int j = 0; j < 8; ++j) {
    float w = (col < 40) ? Wlin[col * 128 + kbase + j] : 0.f;
    dst[j] = (unsigned short)rne_bf16(w);
  }
}

// ---------------- aggregation: quarter-wave (16 lanes) per node ------------
// 4-deep unrolled edge loop (4 outstanding uint4 loads/lane).
// Outputs SEPARATE hi and lo bf16 planes (uint4 stores, no packing).
__global__ void aggregate_k(const unsigned short* __restrict__ zb,
                            const int* __restrict__ offsets,
                            const int* __restrict__ esrc,
                            const float* __restrict__ inv_cnt,
                            unsigned short* __restrict__ aggh,
                            unsigned short* __restrict__ aggl, int n) {
  int node = (blockIdx.x * 256 + threadIdx.x) >> 4;
  int l16 = threadIdx.x & 15;
  if (node >= n) return;
  int beg = offsets[node], end = offsets[node + 1];
  float a0 = 0.f, a1 = 0.f, a2 = 0.f, a3 = 0.f;
  float a4 = 0.f, a5 = 0.f, a6 = 0.f, a7 = 0.f;
  int t = beg;
  for (; t + 4 <= end; t += 4) {
    int s0 = esrc[t], s1 = esrc[t + 1], s2 = esrc[t + 2], s3 = esrc[t + 3];
    uint4 d0 = *(const uint4*)(zb + (size_t)s0 * 128 + l16 * 8);
    uint4 d1 = *(const uint4*)(zb + (size_t)s1 * 128 + l16 * 8);
    uint4 d2 = *(const uint4*)(zb + (size_t)s2 * 128 + l16 * 8);
    uint4 d3 = *(const uint4*)(zb + (size_t)s3 * 128 + l16 * 8);
    a0 += bf_lo(d0.x); a1 += bf_hi(d0.x); a2 += bf_lo(d0.y); a3 += bf_hi(d0.y);
    a4 += bf_lo(d0.z); a5 += bf_hi(d0.z); a6 += bf_lo(d0.w); a7 += bf_hi(d0.w);
    a0 += bf_lo(d1.x); a1 += bf_hi(d1.x); a2 += bf_lo(d1.y); a3 += bf_hi(d1.y);
    a4 += bf_lo(d1.z); a5 += bf_hi(d1.z); a6 += bf_lo(d1.w); a7 += bf_hi(d1.w);
    a0 += bf_lo(d2.x); a1 += bf_hi(d2.x); a2 += bf_lo(d2.y); a3 += bf_hi(d2.y);
    a4 += bf_lo(d2.z); a5 += bf_hi(d2.z); a6 += bf_lo(d2.w); a7 += bf_hi(d2.w);
    a0 += bf_lo(d3.x); a1 += bf_hi(d3.x); a2 += bf_lo(d3.y); a3 += bf_hi(d3.y);
    a4 += bf_lo(d3.z); a5 += bf_hi(d3.z); a6 += bf_lo(d3.w); a7 += bf_hi(d3.w);
  }
  for (; t + 2 <= end; t += 2) {
    int s0 = esrc[t], s1 = esrc[t + 1];
    uint4 d0 = *(const uint4*)(zb + (size_t)s0 * 128 + l16 * 8);
    uint4 d1 = *(const uint4*)(zb + (size_t)s1 * 128 + l16 * 8);
    a0 += bf_lo(d0.x); a1 += bf_hi(d0.x); a2 += bf_lo(d0.y); a3 += bf_hi(d0.y);
    a4 += bf_lo(d0.z); a5 += bf_hi(d0.z); a6 += bf_lo(d0.w); a7 += bf_hi(d0.w);
    a0 += bf_lo(d1.x); a1 += bf_hi(d1.x); a2 += bf_lo(d1.y); a3 += bf_hi(d1.y);
    a4 += bf_lo(d1.z); a5 += bf_hi(d1.z); a6 += bf_lo(d1.w); a7 += bf_hi(d1.w);
  }
  if (t < end) {
    int s0 = esrc[t];
    uint4 d0 = *(const uint4*)(zb + (size_t)s0 * 128 + l16 * 8);
    a0 += bf_lo(d0.x); a1 += bf_hi(d0.x); a2 += bf_lo(d0.y); a3 += bf_hi(d0.y);
    a4 += bf_lo(d0.z); a5 += bf_hi(d0.z); a6 += bf_lo(d0.w); a7 += bf_hi(d0.w);
  }
  float ic = inv_cnt[node];
  a0 *= ic; a1 *= ic; a2 *= ic; a3 *= ic;
  a4 *= ic; a5 *= ic; a6 *= ic; a7 *= ic;
  unsigned h0 = rne_bf16(a0), h1 = rne_bf16(a1), h2 = rne_bf16(a2), h3 = rne_bf16(a3);
  unsigned h4 = rne_bf16(a4), h5 = rne_bf16(a5), h6 = rne_bf16(a6), h7 = rne_bf16(a7);
  uint4 hv, lv;
  hv.x = h0 | (h1 << 16); hv.y = h2 | (h3 << 16);
  hv.z = h4 | (h5 << 16); hv.w = h6 | (h7 << 16);
  lv.x = rne_bf16(a0 - __uint_as_float(h0 << 16)) | (rne_bf16(a1 - __uint_as_float(h1 << 16)) << 16);
  lv.y = rne_bf16(a2 - __uint_as_float(h2 << 16)) | (rne_bf16(a3 - __uint_as_float(h3 << 16)) << 16);
  lv.z = rne_bf16(a4 - __uint_as_float(h4 << 16)) | (rne_bf16(a5 - __uint_as_float(h5 << 16)) << 16);
  lv.w = rne_bf16(a6 - __uint_as_float(h6 << 16)) | (rne_bf16(a7 - __uint_as_float(h7 << 16)) << 16);
  *(uint4*)(aggh + (size_t)node * 128 + l16 * 8) = hv;
  *(uint4*)(aggl + (size_t)node * 128 + l16 * 8) = lv;
}

// ---------------- SAGE layer via MFMA ----------------
// A: k<128 agg (hi plane + lo plane), k>=128 zb (single bf16).
// Staging is three pure uint4->LDS copies (no unpack VALU).
__global__ __launch_bounds__(256) void sage_layer_mfma_k(
    const unsigned short* __restrict__ zb,
    const unsigned short* __restrict__ aggh, const unsigned short* __restrict__ aggl,
    const unsigned short* __restrict__ wf, const float* __restrict__ bl,
    unsigned short* __restrict__ out_bf, int n, int ntiles) {
  __shared__ unsigned short Ah_s[32 * 256];
  __shared__ unsigned short Al_s[32 * 128];
  __shared__ float psum[2][4][16];

  const int lane = threadIdx.x & 63;
  const int wv = threadIdx.x >> 6;
  const int g = lane >> 4;
  const int rl = lane & 15;

  const bf16x8* wfv = (const bf16x8*)wf;
  const int t0 = wv * 2, t1 = wv * 2 + 1;
  bf16x8 Bh0[8], Bh1[8], Bl0[8], Bl1[8];
#pragma unroll
  for (int c = 0; c < 8; ++c) {
    Bh0[c] = wfv[((0 * 8 + t0) * 8 + c) * 64 + lane];
    Bh1[c] = wfv[((0 * 8 + t1) * 8 + c) * 64 + lane];
    Bl0[c] = wfv[((1 * 8 + t0) * 8 + c) * 64 + lane];
    Bl1[c] = wfv[((1 * 8 + t1) * 8 + c) * 64 + lane];
  }
  const float b0 = bl[t0 * 16 + rl];
  const float b1 = bl[t1 * 16 + rl];

  char* pAh = (char*)Ah_s;
  char* pAl = (char*)Al_s;

  for (int tile = blockIdx.x; tile < ntiles; tile += gridDim.x) {
    const int v0 = tile * 32;

    // ---- stage: agg-hi (k<128), z (k>=128), agg-lo -> pure copies
#pragma unroll
    for (int q = 0; q < 2; ++q) {
      int lin = q * 2048 + threadIdx.x * 8;   // ushort idx in [32][128]
      int r = lin >> 7;
      int col = lin & 127;
      int v = v0 + r; v = (v < n) ? v : (n - 1);
      int swz = (r & 7) << 4;
      uint4 dh = *(const uint4*)(aggh + (size_t)v * 128 + col);
      uint4 dz = *(const uint4*)(zb + (size_t)v * 128 + col);
      uint4 dl = *(const uint4*)(aggl + (size_t)v * 128 + col);
      *(uint4*)(pAh + ((r * 512 + col * 2) ^ swz)) = dh;
      *(uint4*)(pAh + ((r * 512 + 256 + col * 2) ^ swz)) = dz;
      *(uint4*)(pAl + ((r * 256 + col * 2) ^ swz)) = dl;
    }
    __syncthreads();

#pragma unroll
    for (int s = 0; s < 2; ++s) {
      f32x4 a0 = {0.f, 0.f, 0.f, 0.f};
      f32x4 a1 = {0.f, 0.f, 0.f, 0.f};
      const int rowH = (s * 16 + rl) * 512;
      const int rowL = (s * 16 + rl) * 256;
      const int swz = (rl & 7) << 4;
#pragma unroll
      for (int c = 0; c < 4; ++c) {
        int offH = (rowH + c * 64 + g * 16) ^ swz;
        int offL = (rowL + c * 64 + g * 16) ^ swz;
        bf16x8 ah = *(const bf16x8*)(pAh + offH);
        bf16x8 al = *(const bf16x8*)(pAl + offL);
        a0 = MFMA16(ah, Bh0[c], a0); a1 = MFMA16(ah, Bh1[c], a1);
        a0 = MFMA16(ah, Bl0[c], a0); a1 = MFMA16(ah, Bl1[c], a1);
        a0 = MFMA16(al, Bh0[c], a0); a1 = MFMA16(al, Bh1[c], a1);
      }
#pragma unroll
      for (int c = 4; c < 8; ++c) {
        int offH = (rowH + c * 64 + g * 16) ^ swz;
        bf16x8 ah = *(const bf16x8*)(pAh + offH);
        a0 = MFMA16(ah, Bh0[c], a0); a1 = MFMA16(ah, Bh1[c], a1);
        a0 = MFMA16(ah, Bl0[c], a0); a1 = MFMA16(ah, Bl1[c], a1);
      }
      float pr[4];
#pragma unroll
      for (int j = 0; j < 4; ++j) {
        a0[j] += b0; a1[j] += b1;
        pr[j] = a0[j] * a0[j] + a1[j] * a1[j];
      }
#pragma unroll
      for (int m = 1; m < 16; m <<= 1) {
#pragma unroll
        for (int j = 0; j < 4; ++j) pr[j] += __shfl_xor(pr[j], m);
      }
      if (rl == 0) {
#pragma unroll
        for (int j = 0; j < 4; ++j) psum[s][wv][g * 4 + j] = pr[j];
      }
      __syncthreads();
#pragma unroll
      for (int j = 0; j < 4; ++j) {
        int row16 = g * 4 + j;
        float tot = psum[s][0][row16] + psum[s][1][row16] +
                    psum[s][2][row16] + psum[s][3][row16];
        float inv = 1.0f / fmaxf(sqrtf(tot), 1e-12f);
        int v = v0 + s * 16 + row16;
        if (v < n) {
          float o0 = fmaxf(a0[j] * inv, 0.f);
          float o1 = fmaxf(a1[j] * inv, 0.f);
          out_bf[(size_t)v * 128 + t0 * 16 + rl] = (unsigned short)rne_bf16(o0);
          out_bf[(size_t)v * 128 + t1 * 16 + rl] = (unsigned short)rne_bf16(o1);
        }
      }
    }
    __syncthreads();
  }
}

// ---------------- final linear via MFMA ----------------
__global__ __launch_bounds__(256, 4) void final_linear_mfma_k(
    const unsigned short* __restrict__ zb, const unsigned short* __restrict__ wlf,
    const float* __restrict__ blin, float* __restrict__ out, int n, int ntiles) {
  __shared__ unsigned short Az[64 * 128];

  const int lane = threadIdx.x & 63;
  const int wv = threadIdx.x >> 6;
  const int g = lane >> 4;
  const int rl = lane & 15;

  const bf16x8* wv8 = (const bf16x8*)wlf;
  bf16x8 B[3][4];
#pragma unroll
  for (int t = 0; t < 3; ++t)
#pragma unroll
    for (int c = 0; c < 4; ++c) B[t][c] = wv8[(t * 4 + c) * 64 + lane];
  float bias[3];
#pragma unroll
  for (int t = 0; t < 3; ++t) {
    int col = t * 16 + rl;
    bias[t] = (col < 40) ? blin[col] : 0.f;
  }

  char* pAz = (char*)Az;

  for (int tile = blockIdx.x; tile < ntiles; tile += gridDim.x) {
    const int v0 = tile * 64;
#pragma unroll
    for (int q = 0; q < 4; ++q) {
      int lin = q * 2048 + threadIdx.x * 8;
      int r = lin >> 7;
      int col = lin & 127;
      int v = v0 + r; v = (v < n) ? v : (n - 1);
      uint4 d = *(const uint4*)(zb + (size_t)v * 128 + col);
      int byte = (r * 256 + col * 2) ^ ((r & 7) << 4);
      *(uint4*)(pAz + byte) = d;
    }
    __syncthreads();

    f32x4 acc0 = {0.f, 0.f, 0.f, 0.f};
    f32x4 acc1 = {0.f, 0.f, 0.f, 0.f};
    f32x4 acc2 = {0.f, 0.f, 0.f, 0.f};
    const int rowB = (wv * 16 + rl) * 256;
    const int swz = (rl & 7) << 4;
#pragma unroll
    for (int c = 0; c < 4; ++c) {
      int off = (rowB + c * 64 + g * 16) ^ swz;
      bf16x8 a = *(const bf16x8*)(pAz + off);
      acc0 = MFMA16(a, B[0][c], acc0);
      acc1 = MFMA16(a, B[1][c], acc1);
      acc2 = MFMA16(a, B[2][c], acc2);
    }
#pragma unroll
    for (int j = 0; j < 4; ++j) {
      int v = v0 + wv * 16 + g * 4 + j;
      if (v < n) {
        float* op = out + (size_t)v * 40;
        op[rl] = acc0[j] + bias[0];
        op[16 + rl] = acc1[j] + bias[1];
        if (rl < 8) op[32 + rl] = acc2[j] + bias[2];
      }
    }
    __syncthreads();
  }
}

// ---------------- launch ----------------

extern "C" void kernel_launch(void* const* d_in, const int* in_sizes, int n_in,
                              void* d_out, int out_size, void* d_ws, size_t ws_size,
                              hipStream_t stream) {
  const float* x    = (const float*)d_in[0];
  const int*   ei   = (const int*)d_in[1];
  const float* Wl   = (const float*)d_in[2];
  const float* bl   = (const float*)d_in[3];
  const float* Wr   = (const float*)d_in[4];
  const float* Wlin = (const float*)d_in[5];
  const float* blin = (const float*)d_in[6];

  const int N = in_sizes[0] / 128;
  const int E = in_sizes[1] / 2;
  const int D = 128;
  const int NC = (N + 1023) >> 10;

  const int* src = ei;
  const int* dstp = ei + E;

  // workspace layout
  unsigned short* planeA = (unsigned short*)d_ws;            // N*128 bf16
  unsigned short* planeB = planeA + (size_t)N * D;           // N*128 bf16
  unsigned short* aggh   = planeB + (size_t)N * D;           // N*128 bf16 (agg hi)
  unsigned short* aggl   = aggh + (size_t)N * D;             // N*128 bf16 (agg lo)
  float* inv_cnt = (float*)(aggl + (size_t)N * D);           // N
  unsigned short* wlf = (unsigned short*)(inv_cnt + N);      // 6144 ushorts
  unsigned short* Wfrag = wlf + 6144;                        // 3*65536
  int*   offsets = (int*)(Wfrag + 3 * 65536);                // N+1
  int*   esrc    = offsets + N + 1;                          // E
  unsigned* coarse = (unsigned*)(esrc + E);                  // E
  int*   cbase   = (int*)(coarse + E);                       // 129
  int*   gcur    = cbase + 129;                              // 128
  int*   ghist   = gcur + 128;                               // 128

  // CSR build
  hipMemsetAsync(ghist, 0, 128 * 4, stream);
  histA_k<<<(E + 2047) / 2048, 256, 0, stream>>>(dstp, ghist, E);
  cscan_k<<<1, 128, 0, stream>>>(ghist, cbase, gcur, E);
  bucketA_k<<<(E + 2047) / 2048, 256, 0, stream>>>(src, dstp, gcur, coarse, E, NC);
  bucketB_k<<<NC, 256, 0, stream>>>(cbase, coarse, esrc, offsets, inv_cnt, N, E);

  // weight prep + bf16 x plane
  wfrag_prep_k<<<96, 256, 0, stream>>>(Wl, Wr, Wfrag);
  wlin_frag_k<<<3, 256, 0, stream>>>(Wlin, wlf);
  to_bf16_k<<<((N * 32) + 255) / 256, 256, 0, stream>>>((const float4*)x, (uint2*)planeA, N * 32);

  const int aggGrid = (N * 16 + 255) / 256;   // 16 threads per node
  const int ntiles = (N + 31) / 32;

  // layer 1
  aggregate_k<<<aggGrid, 256, 0, stream>>>(planeA, offsets, esrc, inv_cnt, aggh, aggl, N);
  sage_layer_mfma_k<<<ntiles, 256, 0, stream>>>(planeA, aggh, aggl, Wfrag + 0 * 65536, bl + 0 * D, planeB, N, ntiles);
  // layer 2
  aggregate_k<<<aggGrid, 256, 0, stream>>>(planeB, offsets, esrc, inv_cnt, aggh, aggl, N);
  sage_layer_mfma_k<<<ntiles, 256, 0, stream>>>(planeB, aggh, aggl, Wfrag + 1 * 65536, bl + 1 * D, planeA, N, ntiles);
  // layer 3
  aggregate_k<<<aggGrid, 256, 0, stream>>>(planeA, offsets, esrc, inv_cnt, aggh, aggl, N);
  sage_layer_mfma_k<<<ntiles, 256, 0, stream>>>(planeA, aggh, aggl, Wfrag + 2 * 65536, bl + 2 * D, planeB, N, ntiles);

  // final linear (MFMA)
  const int ntiles64 = (N + 63) / 64;
  final_linear_mfma_k<<<ntiles64, 256, 0, stream>>>(planeB, wlf, blin, (float*)d_out, N, ntiles64);
}

// Round 11
// 376.412 us; speedup vs baseline: 1.6694x; 1.1310x over previous
//
#include <hip/hip_runtime.h>

// ---------------------------------------------------------------------------
// GraphSAGE 3-layer forward.
//   CSR build (capacity-padded coarse bucket, no pre-histogram) -> bf16 planes
//   -> per-layer: aggregate(mean, quarter-wave/node, 4-deep MLP, bf16 agg plane)
//   -> MFMA GEMM [agg|z](bf16) @ [Wl;Wr]^T (weights hi/lo) + bias + L2norm + relu
//   -> final linear (MFMA).
// NOTE: sage keeps 128 VGPR resident B-fragments -> no min-waves launch bound
// (R8: VGPR cap -> spills -> 3x HBM). Aggregate is fabric-bound (~2.9 TB/s
// random gather, R10 diagnostic) - do not chase it with ILP tweaks.
// ---------------------------------------------------------------------------

typedef __bf16 bf16x8 __attribute__((ext_vector_type(8)));
typedef float  f32x4  __attribute__((ext_vector_type(4)));

#define MFMA16(a, b, c) __builtin_amdgcn_mfma_f32_16x16x32_bf16((a), (b), (c), 0, 0, 0)

__device__ __forceinline__ unsigned rne_bf16(float f) {
  unsigned u = __float_as_uint(f);
  unsigned r = u + 0x7FFFu + ((u >> 16) & 1u);
  return r >> 16;
}

__device__ __forceinline__ float bf_lo(unsigned u) { return __uint_as_float(u << 16); }
__device__ __forceinline__ float bf_hi(unsigned u) { return __uint_as_float(u & 0xFFFF0000u); }

// ---------------- CSR build ----------------
// pack = src | ((dst & 1023) << 17); requires N < 2^17, N/1024 <= 128.

// gcur[b] = b*cap (capacity-padded coarse regions)
__global__ void gcur_init_k(int* __restrict__ gcur, int cap) {
  gcur[threadIdx.x] = threadIdx.x * cap;
}

__global__ __launch_bounds__(256) void bucketA_k(
    const int* __restrict__ src, const int* __restrict__ dst,
    int* __restrict__ gcur, unsigned* __restrict__ coarse, int E, int nc) {
  __shared__ int hist[128];
  __shared__ int sd[128];
  __shared__ int lpos[128];
  __shared__ int gbase[128];
  __shared__ unsigned stage[2048];
  __shared__ unsigned char sbuck[2048];

  const int tid = threadIdx.x;
  const int e0 = blockIdx.x * 2048;

  if (tid < 128) hist[tid] = 0;
  __syncthreads();

  int bv[8], pk[8];
#pragma unroll
  for (int j = 0; j < 8; ++j) {
    int e = e0 + j * 256 + tid;
    bv[j] = -1;
    if (e < E) {
      int s = src[e], d = dst[e];
      bv[j] = d >> 10;
      pk[j] = s | ((d & 1023) << 17);
      atomicAdd(&hist[bv[j]], 1);
    }
  }
  __syncthreads();

  if (tid < 128) sd[tid] = hist[tid];
  __syncthreads();
  for (int off = 1; off < 128; off <<= 1) {
    int t = 0;
    if (tid < 128 && tid >= off) t = sd[tid - off];
    __syncthreads();
    if (tid < 128) sd[tid] += t;
    __syncthreads();
  }
  if (tid < 128) {
    int excl = sd[tid] - hist[tid];
    lpos[tid] = excl;
    gbase[tid] = (tid < nc && hist[tid] > 0) ? atomicAdd(&gcur[tid], hist[tid]) : 0;
  }
  __syncthreads();

#pragma unroll
  for (int j = 0; j < 8; ++j) {
    if (bv[j] >= 0) {
      int slot = atomicAdd(&lpos[bv[j]], 1);
      stage[slot] = (unsigned)pk[j];
      sbuck[slot] = (unsigned char)bv[j];
    }
  }
  __syncthreads();

  const int total = sd[127];
  for (int i = tid; i < total; i += 256) {
    int b = sbuck[i];
    int excl = sd[b] - hist[b];
    coarse[gbase[b] + (i - excl)] = stage[i];
  }
}

// 1 block: realized counts = gcur[b]-b*cap; exclusive scan -> cbase[0..128]
__global__ void cscan_k(const int* __restrict__ gcur, int cap, int nc,
                        int* __restrict__ cbase) {
  __shared__ int sd[128];
  const int tid = threadIdx.x;
  int v = (tid < nc) ? (gcur[tid] - tid * cap) : 0;
  sd[tid] = v;
  __syncthreads();
  for (int off = 1; off < 128; off <<= 1) {
    int u = (tid >= off) ? sd[tid - off] : 0;
    __syncthreads();
    sd[tid] += u;
    __syncthreads();
  }
  cbase[tid] = sd[tid] - v;
  if (tid == 127) cbase[128] = sd[127];
}

// one block per coarse bucket: local hist+scan -> offsets/inv_cnt, scatter esrc
__global__ __launch_bounds__(256) void bucketB_k(
    const int* __restrict__ cbase, const int* __restrict__ gcur,
    const unsigned* __restrict__ coarse, int cap,
    int* __restrict__ esrc, int* __restrict__ offsets,
    float* __restrict__ inv_cnt, int n) {
  __shared__ int hcnt[1024];
  __shared__ int cur[1024];
  __shared__ int sd[256];

  const int tid = threadIdx.x;
  const int b = blockIdx.x;
  const int base = b * 1024;
  const int nn = (n - base < 1024) ? (n - base) : 1024;
  const int wbeg = b * cap;
  const int wend = gcur[b];
  const int gdst = cbase[b];

  for (int j = tid; j < 1024; j += 256) hcnt[j] = 0;
  __syncthreads();
  for (int idx = wbeg + tid; idx < wend; idx += 256)
    atomicAdd(&hcnt[coarse[idx] >> 17], 1);
  __syncthreads();

  int b0 = hcnt[tid * 4], b1 = hcnt[tid * 4 + 1];
  int b2 = hcnt[tid * 4 + 2], b3 = hcnt[tid * 4 + 3];
  int tot = b0 + b1 + b2 + b3;
  sd[tid] = tot;
  __syncthreads();
  for (int off = 1; off < 256; off <<= 1) {
    int u = (tid >= off) ? sd[tid - off] : 0;
    __syncthreads();
    sd[tid] += u;
    __syncthreads();
  }
  int excl = gdst + sd[tid] - tot;
  cur[tid * 4]     = excl;
  cur[tid * 4 + 1] = excl + b0;
  cur[tid * 4 + 2] = excl + b0 + b1;
  cur[tid * 4 + 3] = excl + b0 + b1 + b2;
  __syncthreads();

  for (int j = tid; j < nn; j += 256) {
    offsets[base + j] = cur[j];
    int c = hcnt[j] > 1 ? hcnt[j] : 1;
    inv_cnt[base + j] = 1.0f / (float)c;
  }
  if (tid == 0 && base + nn >= n) offsets[n] = gdst + (wend - wbeg);
  __syncthreads();

  for (int idx = wbeg + tid; idx < wend; idx += 256) {
    unsigned p = coarse[idx];
    int pos = atomicAdd(&cur[p >> 17], 1);
    esrc[pos] = (int)(p & 0x1FFFFu);
  }
}

// ---------------- fp32 -> bf16 plane ----------------
__global__ void to_bf16_k(const float4* __restrict__ in, uint2* __restrict__ out, int n4) {
  int i = blockIdx.x * 256 + threadIdx.x;
  if (i >= n4) return;
  float4 f = in[i];
  uint2 o;
  o.x = rne_bf16(f.x) | (rne_bf16(f.y) << 16);
  o.y = rne_bf16(f.z) | (rne_bf16(f.w) << 16);
  out[i] = o;
}

// ---------------- weight fragment prep (hi/lo bf16, MFMA B-layout) ----------
__global__ void wfrag_prep_k(const float* __restrict__ Wl, const float* __restrict__ Wr,
                             unsigned short* __restrict__ wfrag) {
  int id = blockIdx.x * 256 + threadIdx.x;
  if (id >= 3 * 2 * 8 * 8 * 64) return;
  int l = id & 63;
  int c = (id >> 6) & 7;
  int t = (id >> 9) & 7;
  int p = (id >> 12) & 1;
  int layer = id >> 13;
  int col = t * 16 + (l & 15);
  int kbase = c * 32 + (l >> 4) * 8;
  unsigned short* dst = wfrag + (size_t)layer * 65536 +
                        ((((size_t)p * 8 + t) * 8 + c) * 64 + l) * 8;
#pragma unroll
  for (int j = 0; j < 8; ++j) {
    int k = kbase + j;
    float w = (k < 128) ? Wl[layer * 16384 + col * 128 + k]
                        : Wr[layer * 16384 + col * 128 + (k - 128)];
    unsigned h = rne_bf16(w);
    unsigned o;
    if (p == 0) o = h;
    else o = rne_bf16(w - __uint_as_float(h << 16));
    dst[j] = (unsigned short)o;
  }
}

__global__ void wlin_frag_k(const float* __restrict__ Wlin, unsigned short* __restrict__ wlf) {
  int id = blockIdx.x * 256 + threadIdx.x;
  if (id >= 3 * 4 * 64) return;
  int l = id & 63;
  int c = (id >> 6) & 3;
  int t = id >> 8;
  int col = t * 16 + (l & 15);
  int kbase = c * 32 + (l >> 4) * 8;
  unsigned short* dst = wlf + (size_t)id * 8;
#pragma unroll
  for (int j = 0; j < 8; ++j) {
    float w = (col < 40) ? Wlin[col * 128 + kbase + j] : 0.f;
    dst[j] = (unsigned short)rne_bf16(w);
  }
}

// ---------------- aggregation: quarter-wave (16 lanes) per node ------------
// 4-deep unrolled edge loop; output single bf16 plane.
__global__ void aggregate_k(const unsigned short* __restrict__ zb,
                            const int* __restrict__ offsets,
                            const int* __restrict__ esrc,
                            const float* __restrict__ inv_cnt,
                            unsigned short* __restrict__ aggh, int n) {
  int node = (blockIdx.x * 256 + threadIdx.x) >> 4;
  int l16 = threadIdx.x & 15;
  if (node >= n) return;
  int beg = offsets[node], end = offsets[node + 1];
  float a0 = 0.f, a1 = 0.f, a2 = 0.f, a3 = 0.f;
  float a4 = 0.f, a5 = 0.f, a6 = 0.f, a7 = 0.f;
  int t = beg;
  for (; t + 4 <= end; t += 4) {
    int s0 = esrc[t], s1 = esrc[t + 1], s2 = esrc[t + 2], s3 = esrc[t + 3];
    uint4 d0 = *(const uint4*)(zb + (size_t)s0 * 128 + l16 * 8);
    uint4 d1 = *(const uint4*)(zb + (size_t)s1 * 128 + l16 * 8);
    uint4 d2 = *(const uint4*)(zb + (size_t)s2 * 128 + l16 * 8);
    uint4 d3 = *(const uint4*)(zb + (size_t)s3 * 128 + l16 * 8);
    a0 += bf_lo(d0.x); a1 += bf_hi(d0.x); a2 += bf_lo(d0.y); a3 += bf_hi(d0.y);
    a4 += bf_lo(d0.z); a5 += bf_hi(d0.z); a6 += bf_lo(d0.w); a7 += bf_hi(d0.w);
    a0 += bf_lo(d1.x); a1 += bf_hi(d1.x); a2 += bf_lo(d1.y); a3 += bf_hi(d1.y);
    a4 += bf_lo(d1.z); a5 += bf_hi(d1.z); a6 += bf_lo(d1.w); a7 += bf_hi(d1.w);
    a0 += bf_lo(d2.x); a1 += bf_hi(d2.x); a2 += bf_lo(d2.y); a3 += bf_hi(d2.y);
    a4 += bf_lo(d2.z); a5 += bf_hi(d2.z); a6 += bf_lo(d2.w); a7 += bf_hi(d2.w);
    a0 += bf_lo(d3.x); a1 += bf_hi(d3.x); a2 += bf_lo(d3.y); a3 += bf_hi(d3.y);
    a4 += bf_lo(d3.z); a5 += bf_hi(d3.z); a6 += bf_lo(d3.w); a7 += bf_hi(d3.w);
  }
  for (; t + 2 <= end; t += 2) {
    int s0 = esrc[t], s1 = esrc[t + 1];
    uint4 d0 = *(const uint4*)(zb + (size_t)s0 * 128 + l16 * 8);
    uint4 d1 = *(const uint4*)(zb + (size_t)s1 * 128 + l16 * 8);
    a0 += bf_lo(d0.x); a1 += bf_hi(d0.x); a2 += bf_lo(d0.y); a3 += bf_hi(d0.y);
    a4 += bf_lo(d0.z); a5 += bf_hi(d0.z); a6 += bf_lo(d0.w); a7 += bf_hi(d0.w);
    a0 += bf_lo(d1.x); a1 += bf_hi(d1.x); a2 += bf_lo(d1.y); a3 += bf_hi(d1.y);
    a4 += bf_lo(d1.z); a5 += bf_hi(d1.z); a6 += bf_lo(d1.w); a7 += bf_hi(d1.w);
  }
  if (t < end) {
    int s0 = esrc[t];
    uint4 d0 = *(const uint4*)(zb + (size_t)s0 * 128 + l16 * 8);
    a0 += bf_lo(d0.x); a1 += bf_hi(d0.x); a2 += bf_lo(d0.y); a3 += bf_hi(d0.y);
    a4 += bf_lo(d0.z); a5 += bf_hi(d0.z); a6 += bf_lo(d0.w); a7 += bf_hi(d0.w);
  }
  float ic = inv_cnt[node];
  uint4 hv;
  hv.x = rne_bf16(a0 * ic) | (rne_bf16(a1 * ic) << 16);
  hv.y = rne_bf16(a2 * ic) | (rne_bf16(a3 * ic) << 16);
  hv.z = rne_bf16(a4 * ic) | (rne_bf16(a5 * ic) << 16);
  hv.w = rne_bf16(a6 * ic) | (rne_bf16(a7 * ic) << 16);
  *(uint4*)(aggh + (size_t)node * 128 + l16 * 8) = hv;
}

// ---------------- SAGE layer via MFMA ----------------
// A (bf16): k<128 agg plane, k>=128 z plane. Weights hi/lo -> 4 MFMA/chunk.
__global__ __launch_bounds__(256) void sage_layer_mfma_k(
    const unsigned short* __restrict__ zb, const unsigned short* __restrict__ aggh,
    const unsigned short* __restrict__ wf, const float* __restrict__ bl,
    unsigned short* __restrict__ out_bf, int n, int ntiles) {
  __shared__ unsigned short Ah_s[32 * 256];   // 16 KB swizzled [32][256]
  __shared__ float psum[2][4][16];

  const int lane = threadIdx.x & 63;
  const int wv = threadIdx.x >> 6;
  const int g = lane >> 4;
  const int rl = lane & 15;

  const bf16x8* wfv = (const bf16x8*)wf;
  const int t0 = wv * 2, t1 = wv * 2 + 1;
  bf16x8 Bh0[8], Bh1[8], Bl0[8], Bl1[8];
#pragma unroll
  for (int c = 0; c < 8; ++c) {
    Bh0[c] = wfv[((0 * 8 + t0) * 8 + c) * 64 + lane];
    Bh1[c] = wfv[((0 * 8 + t1) * 8 + c) * 64 + lane];
    Bl0[c] = wfv[((1 * 8 + t0) * 8 + c) * 64 + lane];
    Bl1[c] = wfv[((1 * 8 + t1) * 8 + c) * 64 + lane];
  }
  const float b0 = bl[t0 * 16 + rl];
  const float b1 = bl[t1 * 16 + rl];

  char* pAh = (char*)Ah_s;

  for (int tile = blockIdx.x; tile < ntiles; tile += gridDim.x) {
    const int v0 = tile * 32;

    // ---- stage: agg (k<128) + z (k>=128), pure uint4 copies
#pragma unroll
    for (int q = 0; q < 2; ++q) {
      int lin = q * 2048 + threadIdx.x * 8;   // ushort idx in [32][128]
      int r = lin >> 7;
      int col = lin & 127;
      int v = v0 + r; v = (v < n) ? v : (n - 1);
      int swz = (r & 7) << 4;
      uint4 dh = *(const uint4*)(aggh + (size_t)v * 128 + col);
      uint4 dz = *(const uint4*)(zb + (size_t)v * 128 + col);
      *(uint4*)(pAh + ((r * 512 + col * 2) ^ swz)) = dh;
      *(uint4*)(pAh + ((r * 512 + 256 + col * 2) ^ swz)) = dz;
    }
    __syncthreads();

#pragma unroll
    for (int s = 0; s < 2; ++s) {
      f32x4 a0 = {0.f, 0.f, 0.f, 0.f};
      f32x4 a1 = {0.f, 0.f, 0.f, 0.f};
      const int rowH = (s * 16 + rl) * 512;
      const int swz = (rl & 7) << 4;
#pragma unroll
      for (int c = 0; c < 8; ++c) {
        int offH = (rowH + c * 64 + g * 16) ^ swz;
        bf16x8 ah = *(const bf16x8*)(pAh + offH);
        a0 = MFMA16(ah, Bh0[c], a0); a1 = MFMA16(ah, Bh1[c], a1);
        a0 = MFMA16(ah, Bl0[c], a0); a1 = MFMA16(ah, Bl1[c], a1);
      }
      float pr[4];
#pragma unroll
      for (int j = 0; j < 4; ++j) {
        a0[j] += b0; a1[j] += b1;
        pr[j] = a0[j] * a0[j] + a1[j] * a1[j];
      }
#pragma unroll
      for (int m = 1; m < 16; m <<= 1) {
#pragma unroll
        for (int j = 0; j < 4; ++j) pr[j] += __shfl_xor(pr[j], m);
      }
      if (rl == 0) {
#pragma unroll
        for (int j = 0; j < 4; ++j) psum[s][wv][g * 4 + j] = pr[j];
      }
      __syncthreads();
#pragma unroll
      for (int j = 0; j < 4; ++j) {
        int row16 = g * 4 + j;
        float tot = psum[s][0][row16] + psum[s][1][row16] +
                    psum[s][2][row16] + psum[s][3][row16];
        float inv = 1.0f / fmaxf(sqrtf(tot), 1e-12f);
        int v = v0 + s * 16 + row16;
        if (v < n) {
          float o0 = fmaxf(a0[j] * inv, 0.f);
          float o1 = fmaxf(a1[j] * inv, 0.f);
          out_bf[(size_t)v * 128 + t0 * 16 + rl] = (unsigned short)rne_bf16(o0);
          out_bf[(size_t)v * 128 + t1 * 16 + rl] = (unsigned short)rne_bf16(o1);
        }
      }
    }
    __syncthreads();
  }
}

// ---------------- final linear via MFMA ----------------
__global__ __launch_bounds__(256, 4) void final_linear_mfma_k(
    const unsigned short* __restrict__ zb, const unsigned short* __restrict__ wlf,
    const float* __restrict__ blin, float* __restrict__ out, int n, int ntiles) {
  __shared__ unsigned short Az[64 * 128];

  const int lane = threadIdx.x & 63;
  const int wv = threadIdx.x >> 6;
  const int g = lane >> 4;
  const int rl = lane & 15;

  const bf16x8* wv8 = (const bf16x8*)wlf;
  bf16x8 B[3][4];
#pragma unroll
  for (int t = 0; t < 3; ++t)
#pragma unroll
    for (int c = 0; c < 4; ++c) B[t][c] = wv8[(t * 4 + c) * 64 + lane];
  float bias[3];
#pragma unroll
  for (int t = 0; t < 3; ++t) {
    int col = t * 16 + rl;
    bias[t] = (col < 40) ? blin[col] : 0.f;
  }

  char* pAz = (char*)Az;

  for (int tile = blockIdx.x; tile < ntiles; tile += gridDim.x) {
    const int v0 = tile * 64;
#pragma unroll
    for (int q = 0; q < 4; ++q) {
      int lin = q * 2048 + threadIdx.x * 8;
      int r = lin >> 7;
      int col = lin & 127;
      int v = v0 + r; v = (v < n) ? v : (n - 1);
      uint4 d = *(const uint4*)(zb + (size_t)v * 128 + col);
      int byte = (r * 256 + col * 2) ^ ((r & 7) << 4);
      *(uint4*)(pAz + byte) = d;
    }
    __syncthreads();

    f32x4 acc0 = {0.f, 0.f, 0.f, 0.f};
    f32x4 acc1 = {0.f, 0.f, 0.f, 0.f};
    f32x4 acc2 = {0.f, 0.f, 0.f, 0.f};
    const int rowB = (wv * 16 + rl) * 256;
    const int swz = (rl & 7) << 4;
#pragma unroll
    for (int c = 0; c < 4; ++c) {
      int off = (rowB + c * 64 + g * 16) ^ swz;
      bf16x8 a = *(const bf16x8*)(pAz + off);
      acc0 = MFMA16(a, B[0][c], acc0);
      acc1 = MFMA16(a, B[1][c], acc1);
      acc2 = MFMA16(a, B[2][c], acc2);
    }
#pragma unroll
    for (int j = 0; j < 4; ++j) {
      int v = v0 + wv * 16 + g * 4 + j;
      if (v < n) {
        float* op = out + (size_t)v * 40;
        op[rl] = acc0[j] + bias[0];
        op[16 + rl] = acc1[j] + bias[1];
        if (rl < 8) op[32 + rl] = acc2[j] + bias[2];
      }
    }
    __syncthreads();
  }
}

// ---------------- launch ----------------

extern "C" void kernel_launch(void* const* d_in, const int* in_sizes, int n_in,
                              void* d_out, int out_size, void* d_ws, size_t ws_size,
                              hipStream_t stream) {
  const float* x    = (const float*)d_in[0];
  const int*   ei   = (const int*)d_in[1];
  const float* Wl   = (const float*)d_in[2];
  const float* bl   = (const float*)d_in[3];
  const float* Wr   = (const float*)d_in[4];
  const float* Wlin = (const float*)d_in[5];
  const float* blin = (const float*)d_in[6];

  const int N = in_sizes[0] / 128;
  const int E = in_sizes[1] / 2;
  const int D = 128;
  const int NC = (N + 1023) >> 10;
  const int cap = (E + NC - 1) / NC + 4096;   // padded coarse-bucket capacity

  const int* src = ei;
  const int* dstp = ei + E;

  // workspace layout
  unsigned short* planeA = (unsigned short*)d_ws;            // N*128 bf16
  unsigned short* planeB = planeA + (size_t)N * D;           // N*128 bf16
  unsigned short* aggh   = planeB + (size_t)N * D;           // N*128 bf16 (agg)
  float* inv_cnt = (float*)(aggh + (size_t)N * D);           // N
  unsigned short* wlf = (unsigned short*)(inv_cnt + N);      // 6144 ushorts
  unsigned short* Wfrag = wlf + 6144;                        // 3*65536
  int*   offsets = (int*)(Wfrag + 3 * 65536);                // N+1
  int*   esrc    = offsets + N + 1;                          // E
  unsigned* coarse = (unsigned*)(esrc + E);                  // NC*cap
  int*   cbase   = (int*)(coarse + (size_t)NC * cap);        // 129
  int*   gcur    = cbase + 129;                              // 128

  // CSR build (no pre-histogram)
  gcur_init_k<<<1, 128, 0, stream>>>(gcur, cap);
  bucketA_k<<<(E + 2047) / 2048, 256, 0, stream>>>(src, dstp, gcur, coarse, E, NC);
  cscan_k<<<1, 128, 0, stream>>>(gcur, cap, NC, cbase);
  bucketB_k<<<NC, 256, 0, stream>>>(cbase, gcur, coarse, cap, esrc, offsets, inv_cnt, N);

  // weight prep + bf16 x plane
  wfrag_prep_k<<<96, 256, 0, stream>>>(Wl, Wr, Wfrag);
  wlin_frag_k<<<3, 256, 0, stream>>>(Wlin, wlf);
  to_bf16_k<<<((N * 32) + 255) / 256, 256, 0, stream>>>((const float4*)x, (uint2*)planeA, N * 32);

  const int aggGrid = (N * 16 + 255) / 256;   // 16 threads per node
  const int ntiles = (N + 31) / 32;

  // layer 1
  aggregate_k<<<aggGrid, 256, 0, stream>>>(planeA, offsets, esrc, inv_cnt, aggh, N);
  sage_layer_mfma_k<<<ntiles, 256, 0, stream>>>(planeA, aggh, Wfrag + 0 * 65536, bl + 0 * D, planeB, N, ntiles);
  // layer 2
  aggregate_k<<<aggGrid, 256, 0, stream>>>(planeB, offsets, esrc, inv_cnt, aggh, N);
  sage_layer_mfma_k<<<ntiles, 256, 0, stream>>>(planeB, aggh, Wfrag + 1 * 65536, bl + 1 * D, planeA, N, ntiles);
  // layer 3
  aggregate_k<<<aggGrid, 256, 0, stream>>>(planeA, offsets, esrc, inv_cnt, aggh, N);
  sage_layer_mfma_k<<<ntiles, 256, 0, stream>>>(planeA, aggh, Wfrag + 2 * 65536, bl + 2 * D, planeB, N, ntiles);

  // final linear (MFMA)
  const int ntiles64 = (N + 63) / 64;
  final_linear_mfma_k<<<ntiles64, 256, 0, stream>>>(planeB, wlf, blin, (float*)d_out, N, ntiles64);
}

// Round 12
// 366.770 us; speedup vs baseline: 1.7133x; 1.0263x over previous
//
#include <hip/hip_runtime.h>

// ---------------------------------------------------------------------------
// GraphSAGE 3-layer forward.
//   prep (gcur init + weight frags + bf16 x-plane, one kernel)
//   -> CSR build (capacity-padded coarse bucket; bucketB self-scans cbase)
//   -> per-layer: aggregate(mean, quarter-wave/node, 4-deep MLP, bf16 plane)
//      + MFMA sage GEMM (weights hi/lo) + bias + L2norm + relu
//   -> layer 3 fuses the final linear (Wlin via LDS z-tile, direct fp32 out).
// NOTES:
//  - sage keeps 128 VGPR resident B-fragments -> no min-waves launch bound
//    (R8: VGPR cap -> spills -> 3x HBM traffic).
//  - aggregate is fabric-bound (~3 TB/s random gather, R10/R11) - leave it.
// ---------------------------------------------------------------------------

typedef __bf16 bf16x8 __attribute__((ext_vector_type(8)));
typedef float  f32x4  __attribute__((ext_vector_type(4)));

#define MFMA16(a, b, c) __builtin_amdgcn_mfma_f32_16x16x32_bf16((a), (b), (c), 0, 0, 0)

__device__ __forceinline__ unsigned rne_bf16(float f) {
  unsigned u = __float_as_uint(f);
  unsigned r = u + 0x7FFFu + ((u >> 16) & 1u);
  return r >> 16;
}

__device__ __forceinline__ float bf_lo(unsigned u) { return __uint_as_float(u << 16); }
__device__ __forceinline__ float bf_hi(unsigned u) { return __uint_as_float(u & 0xFFFF0000u); }

// ---------------- prep: gcur init + wfrag + wlin frag + x->bf16 ------------
__global__ __launch_bounds__(256) void prep_k(
    const float* __restrict__ x, const float* __restrict__ Wl,
    const float* __restrict__ Wr, const float* __restrict__ Wlin,
    uint2* __restrict__ planeA, unsigned short* __restrict__ wfrag,
    unsigned short* __restrict__ wlf, int* __restrict__ gcur,
    int cap, int n4) {
  const int b = blockIdx.x;
  const int tid = threadIdx.x;
  if (b == 0) {
    if (tid < 128) gcur[tid] = tid * cap;
    return;
  }
  if (b <= 96) {
    // weight fragments (hi/lo bf16, MFMA B-layout), 24576 items
    int id = (b - 1) * 256 + tid;
    int l = id & 63;
    int c = (id >> 6) & 7;
    int t = (id >> 9) & 7;
    int p = (id >> 12) & 1;
    int layer = id >> 13;
    int col = t * 16 + (l & 15);
    int kbase = c * 32 + (l >> 4) * 8;
    unsigned short* dst = wfrag + (size_t)layer * 65536 +
                          ((((size_t)p * 8 + t) * 8 + c) * 64 + l) * 8;
#pragma unroll
    for (int j = 0; j < 8; ++j) {
      int k = kbase + j;
      float w = (k < 128) ? Wl[layer * 16384 + col * 128 + k]
                          : Wr[layer * 16384 + col * 128 + (k - 128)];
      unsigned h = rne_bf16(w);
      unsigned o;
      if (p == 0) o = h;
      else o = rne_bf16(w - __uint_as_float(h << 16));
      dst[j] = (unsigned short)o;
    }
    return;
  }
  if (b == 97) {
    // Wlin fragments, hi-only bf16, 3 col-tiles of 16 (cols >=40 zero)
    for (int id = tid; id < 3 * 4 * 64; id += 256) {
      int l = id & 63;
      int c = (id >> 6) & 3;
      int t = id >> 8;
      int col = t * 16 + (l & 15);
      int kbase = c * 32 + (l >> 4) * 8;
      unsigned short* dst = wlf + (size_t)id * 8;
#pragma unroll
      for (int j = 0; j < 8; ++j) {
        float w = (col < 40) ? Wlin[col * 128 + kbase + j] : 0.f;
        dst[j] = (unsigned short)rne_bf16(w);
      }
    }
    return;
  }
  // x (fp32) -> bf16 plane
  int i = (b - 98) * 256 + tid;
  if (i >= n4) return;
  float4 f = ((const float4*)x)[i];
  uint2 o;
  o.x = rne_bf16(f.x) | (rne_bf16(f.y) << 16);
  o.y = rne_bf16(f.z) | (rne_bf16(f.w) << 16);
  planeA[i] = o;
}

// ---------------- CSR build ----------------
// pack = src | ((dst & 1023) << 17); requires N < 2^17, N/1024 <= 128.

__global__ __launch_bounds__(256) void bucketA_k(
    const int* __restrict__ src, const int* __restrict__ dst,
    int* __restrict__ gcur, unsigned* __restrict__ coarse, int E, int nc) {
  __shared__ int hist[128];
  __shared__ int sd[128];
  __shared__ int lpos[128];
  __shared__ int gbase[128];
  __shared__ unsigned stage[2048];
  __shared__ unsigned char sbuck[2048];

  const int tid = threadIdx.x;
  const int e0 = blockIdx.x * 2048;

  if (tid < 128) hist[tid] = 0;
  __syncthreads();

  int bv[8], pk[8];
#pragma unroll
  for (int j = 0; j < 8; ++j) {
    int e = e0 + j * 256 + tid;
    bv[j] = -1;
    if (e < E) {
      int s = src[e], d = dst[e];
      bv[j] = d >> 10;
      pk[j] = s | ((d & 1023) << 17);
      atomicAdd(&hist[bv[j]], 1);
    }
  }
  __syncthreads();

  if (tid < 128) sd[tid] = hist[tid];
  __syncthreads();
  for (int off = 1; off < 128; off <<= 1) {
    int t = 0;
    if (tid < 128 && tid >= off) t = sd[tid - off];
    __syncthreads();
    if (tid < 128) sd[tid] += t;
    __syncthreads();
  }
  if (tid < 128) {
    int excl = sd[tid] - hist[tid];
    lpos[tid] = excl;
    gbase[tid] = (tid < nc && hist[tid] > 0) ? atomicAdd(&gcur[tid], hist[tid]) : 0;
  }
  __syncthreads();

#pragma unroll
  for (int j = 0; j < 8; ++j) {
    if (bv[j] >= 0) {
      int slot = atomicAdd(&lpos[bv[j]], 1);
      stage[slot] = (unsigned)pk[j];
      sbuck[slot] = (unsigned char)bv[j];
    }
  }
  __syncthreads();

  const int total = sd[127];
  for (int i = tid; i < total; i += 256) {
    int b = sbuck[i];
    int excl = sd[b] - hist[b];
    coarse[gbase[b] + (i - excl)] = stage[i];
  }
}

// one block per coarse bucket: self-scan cbase from gcur, local hist+scan ->
// offsets/inv_cnt, scatter esrc.
__global__ __launch_bounds__(256) void bucketB_k(
    const int* __restrict__ gcur, const unsigned* __restrict__ coarse, int cap,
    int* __restrict__ esrc, int* __restrict__ offsets,
    float* __restrict__ inv_cnt, int n, int nc) {
  __shared__ int hcnt[1024];
  __shared__ int cur[1024];
  __shared__ int sd[256];
  __shared__ int sh_gdst;

  const int tid = threadIdx.x;
  const int b = blockIdx.x;
  const int base = b * 1024;
  const int nn = (n - base < 1024) ? (n - base) : 1024;
  const int wbeg = b * cap;
  const int wend = gcur[b];

  // redundant 128-wide scan of realized counts -> this block's dest base
  if (tid < 128) {
    int v = (tid < nc) ? (gcur[tid] - tid * cap) : 0;
    sd[tid] = v;
  }
  __syncthreads();
  for (int off = 1; off < 128; off <<= 1) {
    int u = 0;
    if (tid < 128 && tid >= off) u = sd[tid - off];
    __syncthreads();
    if (tid < 128) sd[tid] += u;
    __syncthreads();
  }
  if (tid == b) sh_gdst = sd[tid] - (wend - wbeg);
  for (int j = tid; j < 1024; j += 256) hcnt[j] = 0;
  __syncthreads();
  const int gdst = sh_gdst;

  for (int idx = wbeg + tid; idx < wend; idx += 256)
    atomicAdd(&hcnt[coarse[idx] >> 17], 1);
  __syncthreads();

  int b0 = hcnt[tid * 4], b1 = hcnt[tid * 4 + 1];
  int b2 = hcnt[tid * 4 + 2], b3 = hcnt[tid * 4 + 3];
  int tot = b0 + b1 + b2 + b3;
  sd[tid] = tot;
  __syncthreads();
  for (int off = 1; off < 256; off <<= 1) {
    int u = (tid >= off) ? sd[tid - off] : 0;
    __syncthreads();
    sd[tid] += u;
    __syncthreads();
  }
  int excl = gdst + sd[tid] - tot;
  cur[tid * 4]     = excl;
  cur[tid * 4 + 1] = excl + b0;
  cur[tid * 4 + 2] = excl + b0 + b1;
  cur[tid * 4 + 3] = excl + b0 + b1 + b2;
  __syncthreads();

  for (int j = tid; j < nn; j += 256) {
    offsets[base + j] = cur[j];
    int c = hcnt[j] > 1 ? hcnt[j] : 1;
    inv_cnt[base + j] = 1.0f / (float)c;
  }
  if (tid == 0 && base + nn >= n) offsets[n] = gdst + (wend - wbeg);
  __syncthreads();

  for (int idx = wbeg + tid; idx < wend; idx += 256) {
    unsigned p = coarse[idx];
    int pos = atomicAdd(&cur[p >> 17], 1);
    esrc[pos] = (int)(p & 0x1FFFFu);
  }
}

// ---------------- aggregation: quarter-wave (16 lanes) per node ------------
__global__ void aggregate_k(const unsigned short* __restrict__ zb,
                            const int* __restrict__ offsets,
                            const int* __restrict__ esrc,
                            const float* __restrict__ inv_cnt,
                            unsigned short* __restrict__ aggh, int n) {
  int node = (blockIdx.x * 256 + threadIdx.x) >> 4;
  int l16 = threadIdx.x & 15;
  if (node >= n) return;
  int beg = offsets[node], end = offsets[node + 1];
  float a0 = 0.f, a1 = 0.f, a2 = 0.f, a3 = 0.f;
  float a4 = 0.f, a5 = 0.f, a6 = 0.f, a7 = 0.f;
  int t = beg;
  for (; t + 4 <= end; t += 4) {
    int s0 = esrc[t], s1 = esrc[t + 1], s2 = esrc[t + 2], s3 = esrc[t + 3];
    uint4 d0 = *(const uint4*)(zb + (size_t)s0 * 128 + l16 * 8);
    uint4 d1 = *(const uint4*)(zb + (size_t)s1 * 128 + l16 * 8);
    uint4 d2 = *(const uint4*)(zb + (size_t)s2 * 128 + l16 * 8);
    uint4 d3 = *(const uint4*)(zb + (size_t)s3 * 128 + l16 * 8);
    a0 += bf_lo(d0.x); a1 += bf_hi(d0.x); a2 += bf_lo(d0.y); a3 += bf_hi(d0.y);
    a4 += bf_lo(d0.z); a5 += bf_hi(d0.z); a6 += bf_lo(d0.w); a7 += bf_hi(d0.w);
    a0 += bf_lo(d1.x); a1 += bf_hi(d1.x); a2 += bf_lo(d1.y); a3 += bf_hi(d1.y);
    a4 += bf_lo(d1.z); a5 += bf_hi(d1.z); a6 += bf_lo(d1.w); a7 += bf_hi(d1.w);
    a0 += bf_lo(d2.x); a1 += bf_hi(d2.x); a2 += bf_lo(d2.y); a3 += bf_hi(d2.y);
    a4 += bf_lo(d2.z); a5 += bf_hi(d2.z); a6 += bf_lo(d2.w); a7 += bf_hi(d2.w);
    a0 += bf_lo(d3.x); a1 += bf_hi(d3.x); a2 += bf_lo(d3.y); a3 += bf_hi(d3.y);
    a4 += bf_lo(d3.z); a5 += bf_hi(d3.z); a6 += bf_lo(d3.w); a7 += bf_hi(d3.w);
  }
  for (; t + 2 <= end; t += 2) {
    int s0 = esrc[t], s1 = esrc[t + 1];
    uint4 d0 = *(const uint4*)(zb + (size_t)s0 * 128 + l16 * 8);
    uint4 d1 = *(const uint4*)(zb + (size_t)s1 * 128 + l16 * 8);
    a0 += bf_lo(d0.x); a1 += bf_hi(d0.x); a2 += bf_lo(d0.y); a3 += bf_hi(d0.y);
    a4 += bf_lo(d0.z); a5 += bf_hi(d0.z); a6 += bf_lo(d0.w); a7 += bf_hi(d0.w);
    a0 += bf_lo(d1.x); a1 += bf_hi(d1.x); a2 += bf_lo(d1.y); a3 += bf_hi(d1.y);
    a4 += bf_lo(d1.z); a5 += bf_hi(d1.z); a6 += bf_lo(d1.w); a7 += bf_hi(d1.w);
  }
  if (t < end) {
    int s0 = esrc[t];
    uint4 d0 = *(const uint4*)(zb + (size_t)s0 * 128 + l16 * 8);
    a0 += bf_lo(d0.x); a1 += bf_hi(d0.x); a2 += bf_lo(d0.y); a3 += bf_hi(d0.y);
    a4 += bf_lo(d0.z); a5 += bf_hi(d0.z); a6 += bf_lo(d0.w); a7 += bf_hi(d0.w);
  }
  float ic = inv_cnt[node];
  uint4 hv;
  hv.x = rne_bf16(a0 * ic) | (rne_bf16(a1 * ic) << 16);
  hv.y = rne_bf16(a2 * ic) | (rne_bf16(a3 * ic) << 16);
  hv.z = rne_bf16(a4 * ic) | (rne_bf16(a5 * ic) << 16);
  hv.w = rne_bf16(a6 * ic) | (rne_bf16(a7 * ic) << 16);
  *(uint4*)(aggh + (size_t)node * 128 + l16 * 8) = hv;
}

// ---------------- SAGE layer via MFMA (optionally fused final linear) ------
// A (bf16): k<128 agg plane, k>=128 z plane. Weights hi/lo -> 4 MFMA/chunk.
// FUSE: epilogue writes bf16 z-tile to LDS; block then computes z@WlinT+b
// directly to fp32 out (no planeB round-trip, no separate final kernel).
template <bool FUSE>
__global__ __launch_bounds__(256) void sage_layer_mfma_k(
    const unsigned short* __restrict__ zb, const unsigned short* __restrict__ aggh,
    const unsigned short* __restrict__ wf, const float* __restrict__ bl,
    unsigned short* __restrict__ out_bf,
    const unsigned short* __restrict__ wlf, const float* __restrict__ blin,
    float* __restrict__ fout, int n, int ntiles) {
  __shared__ unsigned short Ah_s[32 * 256];   // 16 KB swizzled [32][256]
  __shared__ unsigned short Zt_s[32 * 128];   // 8 KB swizzled [32][128] (FUSE)
  __shared__ float psum[2][4][16];

  const int lane = threadIdx.x & 63;
  const int wv = threadIdx.x >> 6;
  const int g = lane >> 4;
  const int rl = lane & 15;

  const bf16x8* wfv = (const bf16x8*)wf;
  const int t0 = wv * 2, t1 = wv * 2 + 1;
  bf16x8 Bh0[8], Bh1[8], Bl0[8], Bl1[8];
#pragma unroll
  for (int c = 0; c < 8; ++c) {
    Bh0[c] = wfv[((0 * 8 + t0) * 8 + c) * 64 + lane];
    Bh1[c] = wfv[((0 * 8 + t1) * 8 + c) * 64 + lane];
    Bl0[c] = wfv[((1 * 8 + t0) * 8 + c) * 64 + lane];
    Bl1[c] = wfv[((1 * 8 + t1) * 8 + c) * 64 + lane];
  }
  const float b0 = bl[t0 * 16 + rl];
  const float b1 = bl[t1 * 16 + rl];

  char* pAh = (char*)Ah_s;
  char* pZt = (char*)Zt_s;
  const bf16x8* wlfv = (const bf16x8*)wlf;

  for (int tile = blockIdx.x; tile < ntiles; tile += gridDim.x) {
    const int v0 = tile * 32;

    // ---- stage: agg (k<128) + z (k>=128), pure uint4 copies
#pragma unroll
    for (int q = 0; q < 2; ++q) {
      int lin = q * 2048 + threadIdx.x * 8;   // ushort idx in [32][128]
      int r = lin >> 7;
      int col = lin & 127;
      int v = v0 + r; v = (v < n) ? v : (n - 1);
      int swz = (r & 7) << 4;
      uint4 dh = *(const uint4*)(aggh + (size_t)v * 128 + col);
      uint4 dz = *(const uint4*)(zb + (size_t)v * 128 + col);
      *(uint4*)(pAh + ((r * 512 + col * 2) ^ swz)) = dh;
      *(uint4*)(pAh + ((r * 512 + 256 + col * 2) ^ swz)) = dz;
    }
    __syncthreads();

#pragma unroll
    for (int s = 0; s < 2; ++s) {
      f32x4 a0 = {0.f, 0.f, 0.f, 0.f};
      f32x4 a1 = {0.f, 0.f, 0.f, 0.f};
      const int rowH = (s * 16 + rl) * 512;
      const int swz = (rl & 7) << 4;
#pragma unroll
      for (int c = 0; c < 8; ++c) {
        int offH = (rowH + c * 64 + g * 16) ^ swz;
        bf16x8 ah = *(const bf16x8*)(pAh + offH);
        a0 = MFMA16(ah, Bh0[c], a0); a1 = MFMA16(ah, Bh1[c], a1);
        a0 = MFMA16(ah, Bl0[c], a0); a1 = MFMA16(ah, Bl1[c], a1);
      }
      float pr[4];
#pragma unroll
      for (int j = 0; j < 4; ++j) {
        a0[j] += b0; a1[j] += b1;
        pr[j] = a0[j] * a0[j] + a1[j] * a1[j];
      }
#pragma unroll
      for (int m = 1; m < 16; m <<= 1) {
#pragma unroll
        for (int j = 0; j < 4; ++j) pr[j] += __shfl_xor(pr[j], m);
      }
      if (rl == 0) {
#pragma unroll
        for (int j = 0; j < 4; ++j) psum[s][wv][g * 4 + j] = pr[j];
      }
      __syncthreads();
#pragma unroll
      for (int j = 0; j < 4; ++j) {
        int row16 = g * 4 + j;
        float tot = psum[s][0][row16] + psum[s][1][row16] +
                    psum[s][2][row16] + psum[s][3][row16];
        float inv = 1.0f / fmaxf(sqrtf(tot), 1e-12f);
        int v = v0 + s * 16 + row16;
        float o0 = fmaxf(a0[j] * inv, 0.f);
        float o1 = fmaxf(a1[j] * inv, 0.f);
        unsigned short q0 = (unsigned short)rne_bf16(o0);
        unsigned short q1 = (unsigned short)rne_bf16(o1);
        if (!FUSE) {
          if (v < n) {
            out_bf[(size_t)v * 128 + t0 * 16 + rl] = q0;
            out_bf[(size_t)v * 128 + t1 * 16 + rl] = q1;
          }
        } else {
          int rloc = s * 16 + row16;
          int sw = (rloc & 7) << 4;
          *(unsigned short*)(pZt + ((rloc * 256 + (t0 * 16 + rl) * 2) ^ sw)) = q0;
          *(unsigned short*)(pZt + ((rloc * 256 + (t1 * 16 + rl) * 2) ^ sw)) = q1;
        }
      }
    }

    if (FUSE) {
      __syncthreads();
      // final linear: z-tile (LDS) @ WlinT + blin -> fp32 out[.,40]
      for (int job = wv; job < 6; job += 4) {
        int s = job / 3, t = job % 3;
        f32x4 acc = {0.f, 0.f, 0.f, 0.f};
        const int rowz = s * 16 + rl;
        const int swzz = (rowz & 7) << 4;
#pragma unroll
        for (int c = 0; c < 4; ++c) {
          bf16x8 a = *(const bf16x8*)(pZt + ((rowz * 256 + c * 64 + g * 16) ^ swzz));
          bf16x8 bw = wlfv[(t * 4 + c) * 64 + lane];
          acc = MFMA16(a, bw, acc);
        }
        int col = t * 16 + rl;
        if (col < 40) {
          float bb = blin[col];
#pragma unroll
          for (int j = 0; j < 4; ++j) {
            int v = v0 + s * 16 + g * 4 + j;
            if (v < n) fout[(size_t)v * 40 + col] = acc[j] + bb;
          }
        }
      }
    }
    __syncthreads();
  }
}

// ---------------- launch ----------------

extern "C" void kernel_launch(void* const* d_in, const int* in_sizes, int n_in,
                              void* d_out, int out_size, void* d_ws, size_t ws_size,
                              hipStream_t stream) {
  const float* x    = (const float*)d_in[0];
  const int*   ei   = (const int*)d_in[1];
  const float* Wl   = (const float*)d_in[2];
  const float* bl   = (const float*)d_in[3];
  const float* Wr   = (const float*)d_in[4];
  const float* Wlin = (const float*)d_in[5];
  const float* blin = (const float*)d_in[6];

  const int N = in_sizes[0] / 128;
  const int E = in_sizes[1] / 2;
  const int D = 128;
  const int NC = (N + 1023) >> 10;
  const int cap = (E + NC - 1) / NC + 4096;   // padded coarse-bucket capacity

  const int* src = ei;
  const int* dstp = ei + E;

  // workspace layout
  unsigned short* planeA = (unsigned short*)d_ws;            // N*128 bf16
  unsigned short* planeB = planeA + (size_t)N * D;           // N*128 bf16
  unsigned short* aggh   = planeB + (size_t)N * D;           // N*128 bf16 (agg)
  float* inv_cnt = (float*)(aggh + (size_t)N * D);           // N
  unsigned short* wlf = (unsigned short*)(inv_cnt + N);      // 6144 ushorts
  unsigned short* Wfrag = wlf + 6144;                        // 3*65536
  int*   offsets = (int*)(Wfrag + 3 * 65536);                // N+1
  int*   esrc    = offsets + N + 1;                          // E
  unsigned* coarse = (unsigned*)(esrc + E);                  // NC*cap
  int*   gcur    = (int*)(coarse + (size_t)NC * cap);        // 128

  // prep (gcur init + weight frags + bf16 x plane) - one kernel
  const int n4 = N * 32;
  prep_k<<<98 + (n4 + 255) / 256, 256, 0, stream>>>(
      x, Wl, Wr, Wlin, (uint2*)planeA, Wfrag, wlf, gcur, cap, n4);

  // CSR build
  bucketA_k<<<(E + 2047) / 2048, 256, 0, stream>>>(src, dstp, gcur, coarse, E, NC);
  bucketB_k<<<NC, 256, 0, stream>>>(gcur, coarse, cap, esrc, offsets, inv_cnt, N, NC);

  const int aggGrid = (N * 16 + 255) / 256;   // 16 threads per node
  const int ntiles = (N + 31) / 32;

  // layer 1
  aggregate_k<<<aggGrid, 256, 0, stream>>>(planeA, offsets, esrc, inv_cnt, aggh, N);
  sage_layer_mfma_k<false><<<ntiles, 256, 0, stream>>>(
      planeA, aggh, Wfrag + 0 * 65536, bl + 0 * D, planeB, wlf, blin, nullptr, N, ntiles);
  // layer 2
  aggregate_k<<<aggGrid, 256, 0, stream>>>(planeB, offsets, esrc, inv_cnt, aggh, N);
  sage_layer_mfma_k<false><<<ntiles, 256, 0, stream>>>(
      planeB, aggh, Wfrag + 1 * 65536, bl + 1 * D, planeA, wlf, blin, nullptr, N, ntiles);
  // layer 3 + fused final linear
  aggregate_k<<<aggGrid, 256, 0, stream>>>(planeA, offsets, esrc, inv_cnt, aggh, N);
  sage_layer_mfma_k<true><<<ntiles, 256, 0, stream>>>(
      planeA, aggh, Wfrag + 2 * 65536, bl + 2 * D, nullptr, wlf, blin,
      (float*)d_out, N, ntiles);
}

// Round 13
// 352.452 us; speedup vs baseline: 1.7829x; 1.0406x over previous
//
#include <hip/hip_runtime.h>

// ---------------------------------------------------------------------------
// GraphSAGE 3-layer forward.
//   prep (gcur init + weight frags + bf16 x-plane, one kernel)
//   -> CSR build (capacity-padded coarse bucket; bucketB self-scans cbase)
//   -> per-layer: aggregate(mean, quarter-wave/node, 4-deep MLP, bf16 plane)
//      + MFMA sage GEMM (weights hi/lo, global_load_lds staging) + L2norm+relu
//   -> layer 3 fuses the final linear (Wlin via LDS z-tile, direct fp32 out).
// NOTES:
//  - sage keeps 128 VGPR resident B-fragments -> no min-waves launch bound
//    (R8: VGPR cap -> spills -> 3x HBM traffic).
//  - aggregate is fabric-bound (~3 TB/s random gather, R10/R11) - leave it.
//  - staging uses global_load_lds w/ pre-swizzled SOURCE addr + linear LDS
//    dest (rule #21: swizzle both-sides-or-neither; gload_lds writes linear).
// ---------------------------------------------------------------------------

typedef __bf16 bf16x8 __attribute__((ext_vector_type(8)));
typedef float  f32x4  __attribute__((ext_vector_type(4)));

#define MFMA16(a, b, c) __builtin_amdgcn_mfma_f32_16x16x32_bf16((a), (b), (c), 0, 0, 0)

__device__ __forceinline__ unsigned rne_bf16(float f) {
  unsigned u = __float_as_uint(f);
  unsigned r = u + 0x7FFFu + ((u >> 16) & 1u);
  return r >> 16;
}

__device__ __forceinline__ float bf_lo(unsigned u) { return __uint_as_float(u << 16); }
__device__ __forceinline__ float bf_hi(unsigned u) { return __uint_as_float(u & 0xFFFF0000u); }

// async 16B global -> LDS (linear dest: wave-uniform base + lane*16)
__device__ __forceinline__ void gload_lds16(const void* g, void* l) {
  __builtin_amdgcn_global_load_lds(
      (const __attribute__((address_space(1))) unsigned int*)g,
      (__attribute__((address_space(3))) unsigned int*)l, 16, 0, 0);
}

// ---------------- prep: gcur init + wfrag + wlin frag + x->bf16 ------------
__global__ __launch_bounds__(256) void prep_k(
    const float* __restrict__ x, const float* __restrict__ Wl,
    const float* __restrict__ Wr, const float* __restrict__ Wlin,
    uint2* __restrict__ planeA, unsigned short* __restrict__ wfrag,
    unsigned short* __restrict__ wlf, int* __restrict__ gcur,
    int cap, int n4) {
  const int b = blockIdx.x;
  const int tid = threadIdx.x;
  if (b == 0) {
    if (tid < 128) gcur[tid] = tid * cap;
    return;
  }
  if (b <= 96) {
    int id = (b - 1) * 256 + tid;
    int l = id & 63;
    int c = (id >> 6) & 7;
    int t = (id >> 9) & 7;
    int p = (id >> 12) & 1;
    int layer = id >> 13;
    int col = t * 16 + (l & 15);
    int kbase = c * 32 + (l >> 4) * 8;
    unsigned short* dst = wfrag + (size_t)layer * 65536 +
                          ((((size_t)p * 8 + t) * 8 + c) * 64 + l) * 8;
#pragma unroll
    for (int j = 0; j < 8; ++j) {
      int k = kbase + j;
      float w = (k < 128) ? Wl[layer * 16384 + col * 128 + k]
                          : Wr[layer * 16384 + col * 128 + (k - 128)];
      unsigned h = rne_bf16(w);
      unsigned o;
      if (p == 0) o = h;
      else o = rne_bf16(w - __uint_as_float(h << 16));
      dst[j] = (unsigned short)o;
    }
    return;
  }
  if (b == 97) {
    for (int id = tid; id < 3 * 4 * 64; id += 256) {
      int l = id & 63;
      int c = (id >> 6) & 3;
      int t = id >> 8;
      int col = t * 16 + (l & 15);
      int kbase = c * 32 + (l >> 4) * 8;
      unsigned short* dst = wlf + (size_t)id * 8;
#pragma unroll
      for (int j = 0; j < 8; ++j) {
        float w = (col < 40) ? Wlin[col * 128 + kbase + j] : 0.f;
        dst[j] = (unsigned short)rne_bf16(w);
      }
    }
    return;
  }
  int i = (b - 98) * 256 + tid;
  if (i >= n4) return;
  float4 f = ((const float4*)x)[i];
  uint2 o;
  o.x = rne_bf16(f.x) | (rne_bf16(f.y) << 16);
  o.y = rne_bf16(f.z) | (rne_bf16(f.w) << 16);
  planeA[i] = o;
}

// ---------------- CSR build ----------------
// pack = src | ((dst & 1023) << 17); requires N < 2^17, N/1024 <= 128.

__global__ __launch_bounds__(256) void bucketA_k(
    const int* __restrict__ src, const int* __restrict__ dst,
    int* __restrict__ gcur, unsigned* __restrict__ coarse, int E, int nc) {
  __shared__ int hist[128];
  __shared__ int sd[128];
  __shared__ int lpos[128];
  __shared__ int gbase[128];
  __shared__ unsigned stage[2048];
  __shared__ unsigned char sbuck[2048];

  const int tid = threadIdx.x;
  const int e0 = blockIdx.x * 2048;

  if (tid < 128) hist[tid] = 0;
  __syncthreads();

  int bv[8], pk[8];
#pragma unroll
  for (int j = 0; j < 8; ++j) {
    int e = e0 + j * 256 + tid;
    bv[j] = -1;
    if (e < E) {
      int s = src[e], d = dst[e];
      bv[j] = d >> 10;
      pk[j] = s | ((d & 1023) << 17);
      atomicAdd(&hist[bv[j]], 1);
    }
  }
  __syncthreads();

  if (tid < 128) sd[tid] = hist[tid];
  __syncthreads();
  for (int off = 1; off < 128; off <<= 1) {
    int t = 0;
    if (tid < 128 && tid >= off) t = sd[tid - off];
    __syncthreads();
    if (tid < 128) sd[tid] += t;
    __syncthreads();
  }
  if (tid < 128) {
    int excl = sd[tid] - hist[tid];
    lpos[tid] = excl;
    gbase[tid] = (tid < nc && hist[tid] > 0) ? atomicAdd(&gcur[tid], hist[tid]) : 0;
  }
  __syncthreads();

#pragma unroll
  for (int j = 0; j < 8; ++j) {
    if (bv[j] >= 0) {
      int slot = atomicAdd(&lpos[bv[j]], 1);
      stage[slot] = (unsigned)pk[j];
      sbuck[slot] = (unsigned char)bv[j];
    }
  }
  __syncthreads();

  const int total = sd[127];
  for (int i = tid; i < total; i += 256) {
    int b = sbuck[i];
    int excl = sd[b] - hist[b];
    coarse[gbase[b] + (i - excl)] = stage[i];
  }
}

__global__ __launch_bounds__(256) void bucketB_k(
    const int* __restrict__ gcur, const unsigned* __restrict__ coarse, int cap,
    int* __restrict__ esrc, int* __restrict__ offsets,
    float* __restrict__ inv_cnt, int n, int nc) {
  __shared__ int hcnt[1024];
  __shared__ int cur[1024];
  __shared__ int sd[256];
  __shared__ int sh_gdst;

  const int tid = threadIdx.x;
  const int b = blockIdx.x;
  const int base = b * 1024;
  const int nn = (n - base < 1024) ? (n - base) : 1024;
  const int wbeg = b * cap;
  const int wend = gcur[b];

  if (tid < 128) {
    int v = (tid < nc) ? (gcur[tid] - tid * cap) : 0;
    sd[tid] = v;
  }
  __syncthreads();
  for (int off = 1; off < 128; off <<= 1) {
    int u = 0;
    if (tid < 128 && tid >= off) u = sd[tid - off];
    __syncthreads();
    if (tid < 128) sd[tid] += u;
    __syncthreads();
  }
  if (tid == b) sh_gdst = sd[tid] - (wend - wbeg);
  for (int j = tid; j < 1024; j += 256) hcnt[j] = 0;
  __syncthreads();
  const int gdst = sh_gdst;

  for (int idx = wbeg + tid; idx < wend; idx += 256)
    atomicAdd(&hcnt[coarse[idx] >> 17], 1);
  __syncthreads();

  int b0 = hcnt[tid * 4], b1 = hcnt[tid * 4 + 1];
  int b2 = hcnt[tid * 4 + 2], b3 = hcnt[tid * 4 + 3];
  int tot = b0 + b1 + b2 + b3;
  sd[tid] = tot;
  __syncthreads();
  for (int off = 1; off < 256; off <<= 1) {
    int u = (tid >= off) ? sd[tid - off] : 0;
    __syncthreads();
    sd[tid] += u;
    __syncthreads();
  }
  int excl = gdst + sd[tid] - tot;
  cur[tid * 4]     = excl;
  cur[tid * 4 + 1] = excl + b0;
  cur[tid * 4 + 2] = excl + b0 + b1;
  cur[tid * 4 + 3] = excl + b0 + b1 + b2;
  __syncthreads();

  for (int j = tid; j < nn; j += 256) {
    offsets[base + j] = cur[j];
    int c = hcnt[j] > 1 ? hcnt[j] : 1;
    inv_cnt[base + j] = 1.0f / (float)c;
  }
  if (tid == 0 && base + nn >= n) offsets[n] = gdst + (wend - wbeg);
  __syncthreads();

  for (int idx = wbeg + tid; idx < wend; idx += 256) {
    unsigned p = coarse[idx];
    int pos = atomicAdd(&cur[p >> 17], 1);
    esrc[pos] = (int)(p & 0x1FFFFu);
  }
}

// ---------------- aggregation: quarter-wave (16 lanes) per node ------------
__global__ void aggregate_k(const unsigned short* __restrict__ zb,
                            const int* __restrict__ offsets,
                            const int* __restrict__ esrc,
                            const float* __restrict__ inv_cnt,
                            unsigned short* __restrict__ aggh, int n) {
  int node = (blockIdx.x * 256 + threadIdx.x) >> 4;
  int l16 = threadIdx.x & 15;
  if (node >= n) return;
  int beg = offsets[node], end = offsets[node + 1];
  float a0 = 0.f, a1 = 0.f, a2 = 0.f, a3 = 0.f;
  float a4 = 0.f, a5 = 0.f, a6 = 0.f, a7 = 0.f;
  int t = beg;
  for (; t + 4 <= end; t += 4) {
    int s0 = esrc[t], s1 = esrc[t + 1], s2 = esrc[t + 2], s3 = esrc[t + 3];
    uint4 d0 = *(const uint4*)(zb + (size_t)s0 * 128 + l16 * 8);
    uint4 d1 = *(const uint4*)(zb + (size_t)s1 * 128 + l16 * 8);
    uint4 d2 = *(const uint4*)(zb + (size_t)s2 * 128 + l16 * 8);
    uint4 d3 = *(const uint4*)(zb + (size_t)s3 * 128 + l16 * 8);
    a0 += bf_lo(d0.x); a1 += bf_hi(d0.x); a2 += bf_lo(d0.y); a3 += bf_hi(d0.y);
    a4 += bf_lo(d0.z); a5 += bf_hi(d0.z); a6 += bf_lo(d0.w); a7 += bf_hi(d0.w);
    a0 += bf_lo(d1.x); a1 += bf_hi(d1.x); a2 += bf_lo(d1.y); a3 += bf_hi(d1.y);
    a4 += bf_lo(d1.z); a5 += bf_hi(d1.z); a6 += bf_lo(d1.w); a7 += bf_hi(d1.w);
    a0 += bf_lo(d2.x); a1 += bf_hi(d2.x); a2 += bf_lo(d2.y); a3 += bf_hi(d2.y);
    a4 += bf_lo(d2.z); a5 += bf_hi(d2.z); a6 += bf_lo(d2.w); a7 += bf_hi(d2.w);
    a0 += bf_lo(d3.x); a1 += bf_hi(d3.x); a2 += bf_lo(d3.y); a3 += bf_hi(d3.y);
    a4 += bf_lo(d3.z); a5 += bf_hi(d3.z); a6 += bf_lo(d3.w); a7 += bf_hi(d3.w);
  }
  for (; t + 2 <= end; t += 2) {
    int s0 = esrc[t], s1 = esrc[t + 1];
    uint4 d0 = *(const uint4*)(zb + (size_t)s0 * 128 + l16 * 8);
    uint4 d1 = *(const uint4*)(zb + (size_t)s1 * 128 + l16 * 8);
    a0 += bf_lo(d0.x); a1 += bf_hi(d0.x); a2 += bf_lo(d0.y); a3 += bf_hi(d0.y);
    a4 += bf_lo(d0.z); a5 += bf_hi(d0.z); a6 += bf_lo(d0.w); a7 += bf_hi(d0.w);
    a0 += bf_lo(d1.x); a1 += bf_hi(d1.x); a2 += bf_lo(d1.y); a3 += bf_hi(d1.y);
    a4 += bf_lo(d1.z); a5 += bf_hi(d1.z); a6 += bf_lo(d1.w); a7 += bf_hi(d1.w);
  }
  if (t < end) {
    int s0 = esrc[t];
    uint4 d0 = *(const uint4*)(zb + (size_t)s0 * 128 + l16 * 8);
    a0 += bf_lo(d0.x); a1 += bf_hi(d0.x); a2 += bf_lo(d0.y); a3 += bf_hi(d0.y);
    a4 += bf_lo(d0.z); a5 += bf_hi(d0.z); a6 += bf_lo(d0.w); a7 += bf_hi(d0.w);
  }
  float ic = inv_cnt[node];
  uint4 hv;
  hv.x = rne_bf16(a0 * ic) | (rne_bf16(a1 * ic) << 16);
  hv.y = rne_bf16(a2 * ic) | (rne_bf16(a3 * ic) << 16);
  hv.z = rne_bf16(a4 * ic) | (rne_bf16(a5 * ic) << 16);
  hv.w = rne_bf16(a6 * ic) | (rne_bf16(a7 * ic) << 16);
  *(uint4*)(aggh + (size_t)node * 128 + l16 * 8) = hv;
}

// ---------------- SAGE layer via MFMA (optionally fused final linear) ------
// LDS image: 32 rows x 512B, row r = [agg row (256B, 16B-block-swizzled by
// b^=(r&7)) | z row (same swizzle)]. Staged via global_load_lds: linear LDS
// dest (wave-uniform base + lane*16), swizzle applied to SOURCE address.
template <bool FUSE>
__global__ __launch_bounds__(256) void sage_layer_mfma_k(
    const unsigned short* __restrict__ zb, const unsigned short* __restrict__ aggh,
    const unsigned short* __restrict__ wf, const float* __restrict__ bl,
    unsigned short* __restrict__ out_bf,
    const unsigned short* __restrict__ wlf, const float* __restrict__ blin,
    float* __restrict__ fout, int n, int ntiles) {
  __shared__ unsigned short Ah_s[32 * 256];              // 16 KB
  __shared__ unsigned short Zt_s[FUSE ? 32 * 128 : 8];   // 8 KB only if FUSE
  __shared__ float psum[2][4][16];

  const int lane = threadIdx.x & 63;
  const int wv = threadIdx.x >> 6;
  const int g = lane >> 4;
  const int rl = lane & 15;

  const bf16x8* wfv = (const bf16x8*)wf;
  const int t0 = wv * 2, t1 = wv * 2 + 1;
  bf16x8 Bh0[8], Bh1[8], Bl0[8], Bl1[8];
#pragma unroll
  for (int c = 0; c < 8; ++c) {
    Bh0[c] = wfv[((0 * 8 + t0) * 8 + c) * 64 + lane];
    Bh1[c] = wfv[((0 * 8 + t1) * 8 + c) * 64 + lane];
    Bl0[c] = wfv[((1 * 8 + t0) * 8 + c) * 64 + lane];
    Bl1[c] = wfv[((1 * 8 + t1) * 8 + c) * 64 + lane];
  }
  const float b0 = bl[t0 * 16 + rl];
  const float b1 = bl[t1 * 16 + rl];

  char* pAh = (char*)Ah_s;
  char* pZt = (char*)Zt_s;
  const bf16x8* wlfv = (const bf16x8*)wlf;

  // staging geometry (per wave-issue wq in [0,16)): LDS bytes wq*1024..+1023,
  // rows 2wq, 2wq+1; lanes 0-15 agg row, 16-31 z row, 32-47 agg r+1, 48-63 z r+1.
  const int rsub = lane >> 5;            // row within pair
  const int hlf = (lane >> 4) & 1;       // 0: agg, 1: z
  const int b16 = lane & 15;             // 16B block within 256B half

  for (int tile = blockIdx.x; tile < ntiles; tile += gridDim.x) {
    const int v0 = tile * 32;

    // ---- stage via global_load_lds (pre-swizzled source, linear LDS dest)
#pragma unroll
    for (int q = 0; q < 4; ++q) {
      int wq = wv * 4 + q;
      int r = wq * 2 + rsub;
      int v = v0 + r; v = (v < n) ? v : (n - 1);
      int sblk = b16 ^ (r & 7);
      const unsigned short* srcp =
          (hlf ? zb : aggh) + (size_t)v * 128 + sblk * 8;
      gload_lds16(srcp, pAh + wq * 1024);
    }
    __syncthreads();

#pragma unroll
    for (int s = 0; s < 2; ++s) {
      f32x4 a0 = {0.f, 0.f, 0.f, 0.f};
      f32x4 a1 = {0.f, 0.f, 0.f, 0.f};
      const int rowH = (s * 16 + rl) * 512;
      const int swz = (rl & 7) << 4;
#pragma unroll
      for (int c = 0; c < 8; ++c) {
        int offH = (rowH + c * 64 + g * 16) ^ swz;
        bf16x8 ah = *(const bf16x8*)(pAh + offH);
        a0 = MFMA16(ah, Bh0[c], a0); a1 = MFMA16(ah, Bh1[c], a1);
        a0 = MFMA16(ah, Bl0[c], a0); a1 = MFMA16(ah, Bl1[c], a1);
      }
      float pr[4];
#pragma unroll
      for (int j = 0; j < 4; ++j) {
        a0[j] += b0; a1[j] += b1;
        pr[j] = a0[j] * a0[j] + a1[j] * a1[j];
      }
#pragma unroll
      for (int m = 1; m < 16; m <<= 1) {
#pragma unroll
        for (int j = 0; j < 4; ++j) pr[j] += __shfl_xor(pr[j], m);
      }
      if (rl == 0) {
#pragma unroll
        for (int j = 0; j < 4; ++j) psum[s][wv][g * 4 + j] = pr[j];
      }
      __syncthreads();
#pragma unroll
      for (int j = 0; j < 4; ++j) {
        int row16 = g * 4 + j;
        float tot = psum[s][0][row16] + psum[s][1][row16] +
                    psum[s][2][row16] + psum[s][3][row16];
        float inv = 1.0f / fmaxf(sqrtf(tot), 1e-12f);
        int v = v0 + s * 16 + row16;
        float o0 = fmaxf(a0[j] * inv, 0.f);
        float o1 = fmaxf(a1[j] * inv, 0.f);
        unsigned short q0 = (unsigned short)rne_bf16(o0);
        unsigned short q1 = (unsigned short)rne_bf16(o1);
        if (!FUSE) {
          if (v < n) {
            out_bf[(size_t)v * 128 + t0 * 16 + rl] = q0;
            out_bf[(size_t)v * 128 + t1 * 16 + rl] = q1;
          }
        } else {
          int rloc = s * 16 + row16;
          int sw = (rloc & 7) << 4;
          *(unsigned short*)(pZt + ((rloc * 256 + (t0 * 16 + rl) * 2) ^ sw)) = q0;
          *(unsigned short*)(pZt + ((rloc * 256 + (t1 * 16 + rl) * 2) ^ sw)) = q1;
        }
      }
    }

    if (FUSE) {
      __syncthreads();
      for (int job = wv; job < 6; job += 4) {
        int s = job / 3, t = job % 3;
        f32x4 acc = {0.f, 0.f, 0.f, 0.f};
        const int rowz = s * 16 + rl;
        const int swzz = (rowz & 7) << 4;
#pragma unroll
        for (int c = 0; c < 4; ++c) {
          bf16x8 a = *(const bf16x8*)(pZt + ((rowz * 256 + c * 64 + g * 16) ^ swzz));
          bf16x8 bw = wlfv[(t * 4 + c) * 64 + lane];
          acc = MFMA16(a, bw, acc);
        }
        int col = t * 16 + rl;
        if (col < 40) {
          float bb = blin[col];
#pragma unroll
          for (int j = 0; j < 4; ++j) {
            int v = v0 + s * 16 + g * 4 + j;
            if (v < n) fout[(size_t)v * 40 + col] = acc[j] + bb;
          }
        }
      }
    }
    __syncthreads();
  }
}

// ---------------- launch ----------------

extern "C" void kernel_launch(void* const* d_in, const int* in_sizes, int n_in,
                              void* d_out, int out_size, void* d_ws, size_t ws_size,
                              hipStream_t stream) {
  const float* x    = (const float*)d_in[0];
  const int*   ei   = (const int*)d_in[1];
  const float* Wl   = (const float*)d_in[2];
  const float* bl   = (const float*)d_in[3];
  const float* Wr   = (const float*)d_in[4];
  const float* Wlin = (const float*)d_in[5];
  const float* blin = (const float*)d_in[6];

  const int N = in_sizes[0] / 128;
  const int E = in_sizes[1] / 2;
  const int D = 128;
  const int NC = (N + 1023) >> 10;
  const int cap = (E + NC - 1) / NC + 4096;   // padded coarse-bucket capacity

  const int* src = ei;
  const int* dstp = ei + E;

  // workspace layout
  unsigned short* planeA = (unsigned short*)d_ws;            // N*128 bf16
  unsigned short* planeB = planeA + (size_t)N * D;           // N*128 bf16
  unsigned short* aggh   = planeB + (size_t)N * D;           // N*128 bf16 (agg)
  float* inv_cnt = (float*)(aggh + (size_t)N * D);           // N
  unsigned short* wlf = (unsigned short*)(inv_cnt + N);      // 6144 ushorts
  unsigned short* Wfrag = wlf + 6144;                        // 3*65536
  int*   offsets = (int*)(Wfrag + 3 * 65536);                // N+1
  int*   esrc    = offsets + N + 1;                          // E
  unsigned* coarse = (unsigned*)(esrc + E);                  // NC*cap
  int*   gcur    = (int*)(coarse + (size_t)NC * cap);        // 128

  // prep (gcur init + weight frags + bf16 x plane)
  const int n4 = N * 32;
  prep_k<<<98 + (n4 + 255) / 256, 256, 0, stream>>>(
      x, Wl, Wr, Wlin, (uint2*)planeA, Wfrag, wlf, gcur, cap, n4);

  // CSR build
  bucketA_k<<<(E + 2047) / 2048, 256, 0, stream>>>(src, dstp, gcur, coarse, E, NC);
  bucketB_k<<<NC, 256, 0, stream>>>(gcur, coarse, cap, esrc, offsets, inv_cnt, N, NC);

  const int aggGrid = (N * 16 + 255) / 256;   // 16 threads per node
  const int ntiles = (N + 31) / 32;
  const int sageGrid = 1024;                  // 4 blocks/CU, grid-stride ~3 tiles

  // layer 1
  aggregate_k<<<aggGrid, 256, 0, stream>>>(planeA, offsets, esrc, inv_cnt, aggh, N);
  sage_layer_mfma_k<false><<<sageGrid, 256, 0, stream>>>(
      planeA, aggh, Wfrag + 0 * 65536, bl + 0 * D, planeB, wlf, blin, nullptr, N, ntiles);
  // layer 2
  aggregate_k<<<aggGrid, 256, 0, stream>>>(planeB, offsets, esrc, inv_cnt, aggh, N);
  sage_layer_mfma_k<false><<<sageGrid, 256, 0, stream>>>(
      planeB, aggh, Wfrag + 1 * 65536, bl + 1 * D, planeA, wlf, blin, nullptr, N, ntiles);
  // layer 3 + fused final linear
  aggregate_k<<<aggGrid, 256, 0, stream>>>(planeA, offsets, esrc, inv_cnt, aggh, N);
  sage_layer_mfma_k<true><<<sageGrid, 256, 0, stream>>>(
      planeA, aggh, Wfrag + 2 * 65536, bl + 2 * D, nullptr, wlf, blin,
      (float*)d_out, N, ntiles);
}